// Round 1
// baseline (16080.621 us; speedup 1.0000x reference)
//
#include <hip/hip_runtime.h>
#include <math.h>

#define TPB 256

// ---------------- direct conv + bias + ReLU (NCHW) ----------------
template<int C,int HIN,int O,int HOUT,int K,int S,int P>
__global__ __launch_bounds__(TPB) void conv_relu_k(
    const float* __restrict__ in, const float* __restrict__ w,
    const float* __restrict__ bias, float* __restrict__ out, int nTotal)
{
  int idx = blockIdx.x*TPB + threadIdx.x;
  if (idx >= nTotal) return;
  int ow = idx % HOUT;
  int t  = idx / HOUT;
  int oh = t % HOUT; t /= HOUT;
  int oc = t % O;
  int b  = t / O;
  const float* wp = w + (size_t)oc*C*K*K;
  const float* ip = in + (size_t)b*C*HIN*HIN;
  float acc = bias[oc];
  int ih0 = oh*S - P;
  int iw0 = ow*S - P;
  for (int c=0;c<C;++c){
    const float* ic = ip + (size_t)c*HIN*HIN;
    const float* wc = wp + c*K*K;
    #pragma unroll
    for (int kh=0;kh<K;++kh){
      int ih = ih0 + kh;
      if (ih < 0 || ih >= HIN) continue;
      const float* ir = ic + (size_t)ih*HIN;
      const float* wr = wc + kh*K;
      #pragma unroll
      for (int kw=0;kw<K;++kw){
        int iw = iw0 + kw;
        if (iw < 0 || iw >= HIN) continue;
        acc = fmaf(ir[iw], wr[kw], acc);
      }
    }
  }
  out[idx] = fmaxf(acc, 0.f);
}

// ---------------- 3x3 stride-2 VALID maxpool ----------------
template<int HIN,int HOUT>
__global__ __launch_bounds__(TPB) void maxpool_k(
    const float* __restrict__ in, float* __restrict__ out, int nTotal)
{
  int idx = blockIdx.x*TPB + threadIdx.x;
  if (idx >= nTotal) return;
  int ow = idx % HOUT;
  int t  = idx / HOUT;
  int oh = t % HOUT;
  int ch = t / HOUT;               // flattened b*C + c
  const float* p = in + ((size_t)ch*HIN + oh*2)*HIN + ow*2;
  float m = -INFINITY;
  #pragma unroll
  for (int i=0;i<3;++i)
    #pragma unroll
    for (int j=0;j<3;++j)
      m = fmaxf(m, p[i*HIN + j]);
  out[idx] = m;
}

// ---------------- gate: feat->relu(72)->logits(8)->top2 softmax ----------------
__global__ __launch_bounds__(128) void gate_k(
    const float* __restrict__ feat, const float* __restrict__ gw1,
    const float* __restrict__ gb1,  const float* __restrict__ gw2,
    const float* __restrict__ gb2,  float* __restrict__ gates)
{
  int b = blockIdx.x;
  int tid = threadIdx.x;
  __shared__ float g[72];
  __shared__ float logits[8];
  if (tid < 72) {
    float acc = gb1[tid];
    const float* f = feat + (size_t)b*9216;
    for (int d=0; d<9216; ++d)
      acc = fmaf(f[d], gw1[(size_t)d*72 + tid], acc);
    g[tid] = fmaxf(acc, 0.f);
  }
  __syncthreads();
  if (tid < 8) {
    float acc = gb2[tid];
    for (int j=0;j<72;++j)
      acc = fmaf(g[j], gw2[(size_t)j*8 + tid], acc);
    logits[tid] = acc;
  }
  __syncthreads();
  if (tid == 0) {
    // top-2 with first-occurrence tie-break (matches jax.lax.top_k)
    int i1 = 0; float v1 = logits[0];
    for (int e=1;e<8;++e) if (logits[e] > v1) { v1 = logits[e]; i1 = e; }
    int i2 = -1; float v2 = -INFINITY;
    for (int e=0;e<8;++e) { if (e==i1) continue; if (logits[e] > v2) { v2 = logits[e]; i2 = e; } }
    float z  = expf(v2 - v1);          // v1 >= v2, stable
    float w1 = 1.f / (1.f + z);
    float w2 = z   / (1.f + z);
    float* gr = gates + (size_t)b*8;
    for (int e=0;e<8;++e) gr[e] = 0.f;
    gr[i1] = w1;
    gr[i2] = w2;
  }
}

// ---------------- expert layer 1: [E,B,288] = relu(feat @ ew1 + eb1) ----------------
__global__ __launch_bounds__(TPB) void expert_h1_k(
    const float* __restrict__ feat, const float* __restrict__ ew1,
    const float* __restrict__ eb1,  const float* __restrict__ gates,
    float* __restrict__ h1)
{
  int idx = blockIdx.x*TPB + threadIdx.x;
  if (idx >= 8*64*288) return;
  int h = idx % 288;
  int t = idx / 288;
  int b = t % 64;
  int e = t / 64;
  if (gates[(size_t)b*8 + e] == 0.f) return;   // exact: gate weight is 0
  float acc = eb1[(size_t)e*288 + h];
  const float* f = feat + (size_t)b*9216;
  const float* w = ew1 + (size_t)e*9216*288 + h;
  for (int d=0; d<9216; ++d)
    acc = fmaf(f[d], w[(size_t)d*288], acc);
  h1[idx] = fmaxf(acc, 0.f);
}

// ---------------- expert layer 2: [E,B,144] = relu(h1 @ ew2 + eb2) ----------------
__global__ __launch_bounds__(TPB) void expert_h2_k(
    const float* __restrict__ h1, const float* __restrict__ ew2,
    const float* __restrict__ eb2, const float* __restrict__ gates,
    float* __restrict__ h2)
{
  int idx = blockIdx.x*TPB + threadIdx.x;
  if (idx >= 8*64*144) return;
  int k = idx % 144;
  int t = idx / 144;
  int b = t % 64;
  int e = t / 64;
  if (gates[(size_t)b*8 + e] == 0.f) return;
  float acc = eb2[(size_t)e*144 + k];
  const float* h = h1 + ((size_t)e*64 + b)*288;
  const float* w = ew2 + (size_t)e*288*144 + k;
  for (int d=0; d<288; ++d)
    acc = fmaf(h[d], w[(size_t)d*144], acc);
  h2[idx] = fmaxf(acc, 0.f);
}

// ---------------- expert layer 3 + gated combine: out[b,o] ----------------
__global__ __launch_bounds__(TPB) void expert_out_k(
    const float* __restrict__ h2, const float* __restrict__ ew3,
    const float* __restrict__ eb3, const float* __restrict__ gates,
    float* __restrict__ out)
{
  int idx = blockIdx.x*TPB + threadIdx.x;
  if (idx >= 64*1000) return;
  int o = idx % 1000;
  int b = idx / 1000;
  float acc = 0.f;
  const float* gr = gates + (size_t)b*8;
  for (int e=0;e<8;++e){
    float ge = gr[e];
    if (ge == 0.f) continue;
    float a = eb3[(size_t)e*1000 + o];
    const float* h = h2 + ((size_t)e*64 + b)*144;
    const float* w = ew3 + (size_t)e*144*1000 + o;
    for (int k=0;k<144;++k)
      a = fmaf(h[k], w[(size_t)k*1000], a);
    acc = fmaf(ge, a, acc);
  }
  out[idx] = acc;
}

static inline int nblk(long long n){ return (int)((n + TPB - 1) / TPB); }

extern "C" void kernel_launch(void* const* d_in, const int* in_sizes, int n_in,
                              void* d_out, int out_size, void* d_ws, size_t ws_size,
                              hipStream_t stream)
{
  const float* x   = (const float*)d_in[0];
  const float* c1w = (const float*)d_in[1];  const float* c1b = (const float*)d_in[2];
  const float* c2w = (const float*)d_in[3];  const float* c2b = (const float*)d_in[4];
  const float* c3w = (const float*)d_in[5];  const float* c3b = (const float*)d_in[6];
  const float* c4w = (const float*)d_in[7];  const float* c4b = (const float*)d_in[8];
  const float* c5w = (const float*)d_in[9];  const float* c5b = (const float*)d_in[10];
  const float* gw1 = (const float*)d_in[11]; const float* gb1 = (const float*)d_in[12];
  const float* gw2 = (const float*)d_in[13]; const float* gb2 = (const float*)d_in[14];
  const float* ew1 = (const float*)d_in[15]; const float* eb1 = (const float*)d_in[16];
  const float* ew2 = (const float*)d_in[17]; const float* eb2 = (const float*)d_in[18];
  const float* ew3 = (const float*)d_in[19]; const float* eb3 = (const float*)d_in[20];
  float* out = (float*)d_out;

  // ---- workspace layout (floats), ping-pong A/B + small C ----
  const long long A_FLOATS = 12390400LL;   // max of a1(12.39M), a2(8.96M), a3(4.15M), a5(2.77M)
  const long long B_FLOATS = 2985984LL;    // max of p1(2.99M), p2(2.08M), a4(2.77M), feat(0.59M)
  float* A = (float*)d_ws;
  float* B = A + A_FLOATS;
  float* Cg = B + B_FLOATS;
  float* gates = Cg;                        // 512
  float* h1    = Cg + 512;                  // 147456
  float* h2    = h1 + 147456;               // 73728
  (void)ws_size; (void)in_sizes; (void)n_in; (void)out_size;

  const int B_ = 64;

  // conv1: x[64,3,224,224] -> A[64,64,55,55], s=4 p=2 k=11
  {
    long long n = (long long)B_*64*55*55;
    conv_relu_k<3,224,64,55,11,4,2><<<nblk(n), TPB, 0, stream>>>(x, c1w, c1b, A, (int)n);
  }
  // pool1: A -> B[64,64,27,27]
  {
    long long n = (long long)B_*64*27*27;
    maxpool_k<55,27><<<nblk(n), TPB, 0, stream>>>(A, B, (int)n);
  }
  // conv2: B[64,64,27,27] -> A[64,192,27,27], s=1 p=2 k=5
  {
    long long n = (long long)B_*192*27*27;
    conv_relu_k<64,27,192,27,5,1,2><<<nblk(n), TPB, 0, stream>>>(B, c2w, c2b, A, (int)n);
  }
  // pool2: A -> B[64,192,13,13]
  {
    long long n = (long long)B_*192*13*13;
    maxpool_k<27,13><<<nblk(n), TPB, 0, stream>>>(A, B, (int)n);
  }
  // conv3: B[64,192,13,13] -> A[64,384,13,13], s=1 p=1 k=3
  {
    long long n = (long long)B_*384*13*13;
    conv_relu_k<192,13,384,13,3,1,1><<<nblk(n), TPB, 0, stream>>>(B, c3w, c3b, A, (int)n);
  }
  // conv4: A[64,384,13,13] -> B[64,256,13,13]
  {
    long long n = (long long)B_*256*13*13;
    conv_relu_k<384,13,256,13,3,1,1><<<nblk(n), TPB, 0, stream>>>(A, c4w, c4b, B, (int)n);
  }
  // conv5: B[64,256,13,13] -> A[64,256,13,13]
  {
    long long n = (long long)B_*256*13*13;
    conv_relu_k<256,13,256,13,3,1,1><<<nblk(n), TPB, 0, stream>>>(B, c5w, c5b, A, (int)n);
  }
  // pool3: A[64,256,13,13] -> B = feat[64,9216]
  {
    long long n = (long long)B_*256*6*6;
    maxpool_k<13,6><<<nblk(n), TPB, 0, stream>>>(A, B, (int)n);
  }
  const float* feat = B;

  // gate
  gate_k<<<B_, 128, 0, stream>>>(feat, gw1, gb1, gw2, gb2, gates);

  // experts (skip gate==0 pairs — exact, reference multiplies them by 0)
  expert_h1_k<<<nblk(8LL*64*288), TPB, 0, stream>>>(feat, ew1, eb1, gates, h1);
  expert_h2_k<<<nblk(8LL*64*144), TPB, 0, stream>>>(h1, ew2, eb2, gates, h2);
  expert_out_k<<<nblk(64LL*1000), TPB, 0, stream>>>(h2, ew3, eb3, gates, out);
}

// Round 2
// 4265.306 us; speedup vs baseline: 3.7701x; 3.7701x over previous
//
#include <hip/hip_runtime.h>
#include <math.h>

#define TPB 256

// =================== conv1: 3ch, 11x11, s4, p2, 224 -> 55 ===================
// thread = (b, oc, oh, ow-group of 8). Register-tiled: 8 independent accs,
// input row loaded as 11 aligned float4 (44 floats), taps reused in-register.
__global__ __launch_bounds__(TPB, 2) void conv1_k(
    const float* __restrict__ in, const float* __restrict__ w,
    const float* __restrict__ bias, float* __restrict__ out)
{
  const int NG = 7;                      // ow groups of 8 (last has 7)
  int idx = blockIdx.x*TPB + threadIdx.x;
  const int total = 64*64*55*NG;
  if (idx >= total) return;
  int g  = idx % NG;
  int t  = idx / NG;
  int oh = t % 55; t /= 55;
  int oc = t % 64;
  int b  = t / 64;

  int ow0 = g*8;
  int iw_al = ow0*4 - 4;                 // 16B-aligned start (ow0*4-4)
  bool edge = (g == 0) || (g == NG-1);
  int nout = (g == NG-1) ? 7 : 8;

  float acc[8];
  #pragma unroll
  for (int j=0;j<8;++j) acc[j] = bias[oc];

  const float* ip = in + (size_t)b*3*224*224;
  const float* wp = w + (size_t)oc*3*121;

  for (int c=0;c<3;++c){
    const float* ic = ip + (size_t)c*224*224;
    const float* wc = wp + c*121;
    #pragma unroll
    for (int kh=0;kh<11;++kh){
      int ih = oh*4 - 2 + kh;
      if (ih < 0 || ih >= 224) continue;
      const float* row = ic + (size_t)ih*224;
      float f[44];
      if (!edge) {
        const float4* r4 = reinterpret_cast<const float4*>(row + iw_al);
        #pragma unroll
        for (int v=0; v<11; ++v){
          float4 q = r4[v];
          f[v*4+0]=q.x; f[v*4+1]=q.y; f[v*4+2]=q.z; f[v*4+3]=q.w;
        }
      } else {
        #pragma unroll
        for (int j=0;j<44;++j){
          int iw = iw_al + j;
          f[j] = (iw >= 0 && iw < 224) ? row[iw] : 0.f;
        }
      }
      const float* wr = wc + kh*11;
      float wv[11];
      #pragma unroll
      for (int kw=0;kw<11;++kw) wv[kw] = wr[kw];
      #pragma unroll
      for (int kw=0;kw<11;++kw)
        #pragma unroll
        for (int j=0;j<8;++j)
          acc[j] = fmaf(f[2 + 4*j + kw], wv[kw], acc[j]);
    }
  }
  float* op = out + (((size_t)b*64 + oc)*55 + oh)*55 + ow0;
  for (int j=0;j<nout;++j) op[j] = fmaxf(acc[j], 0.f);
}

// =================== conv2: 64ch, 5x5, p2, 27x27 ===================
// block = (b, 8 ocs). LDS: 4 ch of zero-padded 31x36 plane. thread = (oc, oh),
// owns full 27-wide output row.
__global__ __launch_bounds__(TPB, 2) void conv2_k(
    const float* __restrict__ in, const float* __restrict__ w,
    const float* __restrict__ bias, float* __restrict__ out)
{
  const int CH = 4, ROWS = 31, STR = 36;      // padded plane 31 x 36
  __shared__ __align__(16) float s[CH*ROWS*STR];   // 17856 B

  int octile = blockIdx.x % 24;
  int b      = blockIdx.x / 24;
  int oc_l   = threadIdx.x & 7;
  int oh     = threadIdx.x >> 3;               // 0..31, active < 27
  int oc     = octile*8 + oc_l;

  float acc[27];
  #pragma unroll
  for (int j=0;j<27;++j) acc[j] = bias[oc];

  const float* ip = in + (size_t)b*64*27*27;

  for (int c0=0; c0<64; c0+=CH){
    __syncthreads();
    // stage CH padded channel planes
    for (int l = threadIdx.x; l < CH*ROWS*STR; l += TPB){
      int ch  = l / (ROWS*STR);
      int rem = l % (ROWS*STR);
      int r   = rem / STR;
      int col = rem % STR;
      int ih = r - 2, iw = col - 2;
      float v = 0.f;
      if (ih >= 0 && ih < 27 && iw >= 0 && iw < 27)
        v = ip[((size_t)(c0+ch)*27 + ih)*27 + iw];
      s[l] = v;
    }
    __syncthreads();
    if (oh < 27){
      #pragma unroll
      for (int c=0;c<CH;++c){
        const float* wc = w + ((size_t)oc*64 + c0 + c)*25;
        #pragma unroll
        for (int kh=0;kh<5;++kh){
          const float* row = &s[c*ROWS*STR + (oh+kh)*STR];
          const float4* r4 = reinterpret_cast<const float4*>(row);
          float f[32];
          #pragma unroll
          for (int v=0; v<8; ++v){
            float4 q = r4[v];
            f[v*4+0]=q.x; f[v*4+1]=q.y; f[v*4+2]=q.z; f[v*4+3]=q.w;
          }
          float wv[5];
          #pragma unroll
          for (int kw=0;kw<5;++kw) wv[kw] = wc[kh*5+kw];
          #pragma unroll
          for (int kw=0;kw<5;++kw)
            #pragma unroll
            for (int j=0;j<27;++j)
              acc[j] = fmaf(f[j+kw], wv[kw], acc[j]);
        }
      }
    }
  }
  if (oh < 27){
    float* op = out + (((size_t)b*192 + oc)*27 + oh)*27;
    #pragma unroll
    for (int j=0;j<27;++j) op[j] = fmaxf(acc[j], 0.f);
  }
}

// =================== 3x3 convs (conv3/4/5): p1, 13x13 ===================
// block = (b, 16 ocs). LDS: 16 ch of zero-padded 15x20 plane. thread = (oc, oh).
template<int C,int O>
__global__ __launch_bounds__(TPB, 2) void conv3x3_k(
    const float* __restrict__ in, const float* __restrict__ w,
    const float* __restrict__ bias, float* __restrict__ out)
{
  const int CH = 16, ROWS = 15, STR = 20;     // padded plane 15 x 20
  __shared__ __align__(16) float s[CH*ROWS*STR];   // 19200 B

  const int NT = O/16;
  int octile = blockIdx.x % NT;
  int b      = blockIdx.x / NT;
  int oc_l   = threadIdx.x & 15;
  int oh     = threadIdx.x >> 4;               // 0..15, active < 13
  int oc     = octile*16 + oc_l;

  float acc[13];
  #pragma unroll
  for (int j=0;j<13;++j) acc[j] = bias[oc];

  const float* ip = in + (size_t)b*C*13*13;

  for (int c0=0; c0<C; c0+=CH){
    __syncthreads();
    for (int l = threadIdx.x; l < CH*ROWS*STR; l += TPB){
      int ch  = l / (ROWS*STR);
      int rem = l % (ROWS*STR);
      int r   = rem / STR;
      int col = rem % STR;
      int ih = r - 1, iw = col - 1;
      float v = 0.f;
      if (ih >= 0 && ih < 13 && iw >= 0 && iw < 13)
        v = ip[((size_t)(c0+ch)*13 + ih)*13 + iw];
      s[l] = v;
    }
    __syncthreads();
    if (oh < 13){
      #pragma unroll
      for (int c=0;c<CH;++c){
        const float* wc = w + ((size_t)oc*C + c0 + c)*9;
        float wv[9];
        #pragma unroll
        for (int q=0;q<9;++q) wv[q] = wc[q];
        #pragma unroll
        for (int kh=0;kh<3;++kh){
          const float* row = &s[c*ROWS*STR + (oh+kh)*STR];
          const float4* r4 = reinterpret_cast<const float4*>(row);
          float f[16];
          #pragma unroll
          for (int v=0; v<4; ++v){
            float4 q = r4[v];
            f[v*4+0]=q.x; f[v*4+1]=q.y; f[v*4+2]=q.z; f[v*4+3]=q.w;
          }
          #pragma unroll
          for (int kw=0;kw<3;++kw)
            #pragma unroll
            for (int j=0;j<13;++j)
              acc[j] = fmaf(f[j+kw], wv[kh*3+kw], acc[j]);
        }
      }
    }
  }
  if (oh < 13){
    float* op = out + (((size_t)b*O + oc)*13 + oh)*13;
    #pragma unroll
    for (int j=0;j<13;++j) op[j] = fmaxf(acc[j], 0.f);
  }
}

// ---------------- 3x3 stride-2 VALID maxpool ----------------
template<int HIN,int HOUT>
__global__ __launch_bounds__(TPB) void maxpool_k(
    const float* __restrict__ in, float* __restrict__ out, int nTotal)
{
  int idx = blockIdx.x*TPB + threadIdx.x;
  if (idx >= nTotal) return;
  int ow = idx % HOUT;
  int t  = idx / HOUT;
  int oh = t % HOUT;
  int ch = t / HOUT;
  const float* p = in + ((size_t)ch*HIN + oh*2)*HIN + ow*2;
  float m = -INFINITY;
  #pragma unroll
  for (int i=0;i<3;++i)
    #pragma unroll
    for (int j=0;j<3;++j)
      m = fmaxf(m, p[i*HIN + j]);
  out[idx] = m;
}

// ---------------- gate ----------------
__global__ __launch_bounds__(128) void gate_k(
    const float* __restrict__ feat, const float* __restrict__ gw1,
    const float* __restrict__ gb1,  const float* __restrict__ gw2,
    const float* __restrict__ gb2,  float* __restrict__ gates)
{
  int b = blockIdx.x;
  int tid = threadIdx.x;
  __shared__ float g[72];
  __shared__ float logits[8];
  if (tid < 72) {
    float acc = gb1[tid];
    const float* f = feat + (size_t)b*9216;
    for (int d=0; d<9216; ++d)
      acc = fmaf(f[d], gw1[(size_t)d*72 + tid], acc);
    g[tid] = fmaxf(acc, 0.f);
  }
  __syncthreads();
  if (tid < 8) {
    float acc = gb2[tid];
    for (int j=0;j<72;++j)
      acc = fmaf(g[j], gw2[(size_t)j*8 + tid], acc);
    logits[tid] = acc;
  }
  __syncthreads();
  if (tid == 0) {
    int i1 = 0; float v1 = logits[0];
    for (int e=1;e<8;++e) if (logits[e] > v1) { v1 = logits[e]; i1 = e; }
    int i2 = -1; float v2 = -INFINITY;
    for (int e=0;e<8;++e) { if (e==i1) continue; if (logits[e] > v2) { v2 = logits[e]; i2 = e; } }
    float z  = expf(v2 - v1);
    float w1 = 1.f / (1.f + z);
    float w2 = z   / (1.f + z);
    float* gr = gates + (size_t)b*8;
    for (int e=0;e<8;++e) gr[e] = 0.f;
    gr[i1] = w1;
    gr[i2] = w2;
  }
}

// ---------------- experts ----------------
__global__ __launch_bounds__(TPB) void expert_h1_k(
    const float* __restrict__ feat, const float* __restrict__ ew1,
    const float* __restrict__ eb1,  const float* __restrict__ gates,
    float* __restrict__ h1)
{
  int idx = blockIdx.x*TPB + threadIdx.x;
  if (idx >= 8*64*288) return;
  int h = idx % 288;
  int t = idx / 288;
  int b = t % 64;
  int e = t / 64;
  if (gates[(size_t)b*8 + e] == 0.f) return;
  float acc = eb1[(size_t)e*288 + h];
  const float* f = feat + (size_t)b*9216;
  const float* w = ew1 + (size_t)e*9216*288 + h;
  for (int d=0; d<9216; ++d)
    acc = fmaf(f[d], w[(size_t)d*288], acc);
  h1[idx] = fmaxf(acc, 0.f);
}

__global__ __launch_bounds__(TPB) void expert_h2_k(
    const float* __restrict__ h1, const float* __restrict__ ew2,
    const float* __restrict__ eb2, const float* __restrict__ gates,
    float* __restrict__ h2)
{
  int idx = blockIdx.x*TPB + threadIdx.x;
  if (idx >= 8*64*144) return;
  int k = idx % 144;
  int t = idx / 144;
  int b = t % 64;
  int e = t / 64;
  if (gates[(size_t)b*8 + e] == 0.f) return;
  float acc = eb2[(size_t)e*144 + k];
  const float* h = h1 + ((size_t)e*64 + b)*288;
  const float* w = ew2 + (size_t)e*288*144 + k;
  for (int d=0; d<288; ++d)
    acc = fmaf(h[d], w[(size_t)d*144], acc);
  h2[idx] = fmaxf(acc, 0.f);
}

__global__ __launch_bounds__(TPB) void expert_out_k(
    const float* __restrict__ h2, const float* __restrict__ ew3,
    const float* __restrict__ eb3, const float* __restrict__ gates,
    float* __restrict__ out)
{
  int idx = blockIdx.x*TPB + threadIdx.x;
  if (idx >= 64*1000) return;
  int o = idx % 1000;
  int b = idx / 1000;
  float acc = 0.f;
  const float* gr = gates + (size_t)b*8;
  for (int e=0;e<8;++e){
    float ge = gr[e];
    if (ge == 0.f) continue;
    float a = eb3[(size_t)e*1000 + o];
    const float* h = h2 + ((size_t)e*64 + b)*144;
    const float* w = ew3 + (size_t)e*144*1000 + o;
    for (int k=0;k<144;++k)
      a = fmaf(h[k], w[(size_t)k*1000], a);
    acc = fmaf(ge, a, acc);
  }
  out[idx] = acc;
}

static inline int nblk(long long n){ return (int)((n + TPB - 1) / TPB); }

extern "C" void kernel_launch(void* const* d_in, const int* in_sizes, int n_in,
                              void* d_out, int out_size, void* d_ws, size_t ws_size,
                              hipStream_t stream)
{
  const float* x   = (const float*)d_in[0];
  const float* c1w = (const float*)d_in[1];  const float* c1b = (const float*)d_in[2];
  const float* c2w = (const float*)d_in[3];  const float* c2b = (const float*)d_in[4];
  const float* c3w = (const float*)d_in[5];  const float* c3b = (const float*)d_in[6];
  const float* c4w = (const float*)d_in[7];  const float* c4b = (const float*)d_in[8];
  const float* c5w = (const float*)d_in[9];  const float* c5b = (const float*)d_in[10];
  const float* gw1 = (const float*)d_in[11]; const float* gb1 = (const float*)d_in[12];
  const float* gw2 = (const float*)d_in[13]; const float* gb2 = (const float*)d_in[14];
  const float* ew1 = (const float*)d_in[15]; const float* eb1 = (const float*)d_in[16];
  const float* ew2 = (const float*)d_in[17]; const float* eb2 = (const float*)d_in[18];
  const float* ew3 = (const float*)d_in[19]; const float* eb3 = (const float*)d_in[20];
  float* out = (float*)d_out;

  const long long A_FLOATS = 12390400LL;
  const long long B_FLOATS = 2985984LL;
  float* A = (float*)d_ws;
  float* B = A + A_FLOATS;
  float* Cg = B + B_FLOATS;
  float* gates = Cg;
  float* h1    = Cg + 512;
  float* h2    = h1 + 147456;
  (void)ws_size; (void)in_sizes; (void)n_in; (void)out_size;

  const int B_ = 64;

  // conv1: x -> A [64,64,55,55]
  {
    long long n = 64LL*64*55*7;   // threads (8-wide ow groups)
    conv1_k<<<nblk(n), TPB, 0, stream>>>(x, c1w, c1b, A);
  }
  // pool1: A -> B [64,64,27,27]
  {
    long long n = (long long)B_*64*27*27;
    maxpool_k<55,27><<<nblk(n), TPB, 0, stream>>>(A, B, (int)n);
  }
  // conv2: B -> A [64,192,27,27]
  conv2_k<<<64*24, TPB, 0, stream>>>(B, c2w, c2b, A);
  // pool2: A -> B [64,192,13,13]
  {
    long long n = (long long)B_*192*13*13;
    maxpool_k<27,13><<<nblk(n), TPB, 0, stream>>>(A, B, (int)n);
  }
  // conv3: B -> A [64,384,13,13]
  conv3x3_k<192,384><<<64*24, TPB, 0, stream>>>(B, c3w, c3b, A);
  // conv4: A -> B [64,256,13,13]
  conv3x3_k<384,256><<<64*16, TPB, 0, stream>>>(A, c4w, c4b, B);
  // conv5: B -> A [64,256,13,13]
  conv3x3_k<256,256><<<64*16, TPB, 0, stream>>>(B, c5w, c5b, A);
  // pool3: A -> B = feat [64,9216]
  {
    long long n = (long long)B_*256*6*6;
    maxpool_k<13,6><<<nblk(n), TPB, 0, stream>>>(A, B, (int)n);
  }
  const float* feat = B;

  gate_k<<<B_, 128, 0, stream>>>(feat, gw1, gb1, gw2, gb2, gates);
  expert_h1_k<<<nblk(8LL*64*288), TPB, 0, stream>>>(feat, ew1, eb1, gates, h1);
  expert_h2_k<<<nblk(8LL*64*144), TPB, 0, stream>>>(h1, ew2, eb2, gates, h2);
  expert_out_k<<<nblk(64LL*1000), TPB, 0, stream>>>(h2, ew3, eb3, gates, out);
}

// Round 3
// 3059.861 us; speedup vs baseline: 5.2553x; 1.3940x over previous
//
#include <hip/hip_runtime.h>
#include <math.h>

#define TPB 256

// =================== conv1 v2: oc-broadcast LDS scheme ===================
// block = (b, oh); 256 thr = 4 waves. lane = oc (0..63), wave q = ow quarter.
// LDS: 3ch x 11 rows x 236 floats (4 front / 8 back zero guards) = 31 KB.
// All 64 lanes of a wave read identical LDS addresses -> broadcast.
#define C1W 236
__global__ __launch_bounds__(256, 3) void conv1_k(
    const float* __restrict__ in, const float* __restrict__ w,
    const float* __restrict__ bias, float* __restrict__ out)
{
  __shared__ __align__(16) float s[33*C1W];
  const int oh = blockIdx.x % 55;
  const int b  = blockIdx.x / 55;
  const int oc = threadIdx.x & 63;
  const int q  = threadIdx.x >> 6;

  // ---- stage 11 padded rows x 3 ch ----
  const int NF4 = 33*(C1W/4);            // 33 rows * 59 float4
  for (int l = threadIdx.x; l < NF4; l += 256){
    int row = l / 59;                    // c*11 + kh
    int p4  = l % 59;
    int kh = row % 11, c = row / 11;
    int ih = oh*4 - 2 + kh;
    int iw0 = p4*4 - 4;                  // p index 0 maps to iw = -4
    float4 v = make_float4(0.f,0.f,0.f,0.f);
    if (ih >= 0 && ih < 224 && iw0 >= 0 && iw0 <= 220)
      v = *reinterpret_cast<const float4*>(in + ((size_t)(b*3 + c)*224 + ih)*224 + iw0);
    *reinterpret_cast<float4*>(&s[row*C1W + p4*4]) = v;
  }
  __syncthreads();

  float acc[14];
  float bb = bias[oc];
  #pragma unroll
  for (int j=0;j<14;++j) acc[j] = bb;
  const float* wp = w + (size_t)oc*363;
  const int base = q*56;                 // aligned window start (float4)

  #pragma unroll 1
  for (int c=0;c<3;++c){
    #pragma unroll
    for (int kh=0;kh<11;++kh){
      const float* srow = &s[(c*11+kh)*C1W + base];
      float f[68];
      #pragma unroll
      for (int v4=0; v4<17; ++v4){
        float4 t = *reinterpret_cast<const float4*>(srow + v4*4);
        f[v4*4+0]=t.x; f[v4*4+1]=t.y; f[v4*4+2]=t.z; f[v4*4+3]=t.w;
      }
      const float* wr = wp + c*121 + kh*11;
      float wv[11];
      #pragma unroll
      for (int kw=0;kw<11;++kw) wv[kw] = wr[kw];
      #pragma unroll
      for (int kw=0;kw<11;++kw)
        #pragma unroll
        for (int j=0;j<14;++j)
          acc[j] = fmaf(f[4*j + kw + 2], wv[kw], acc[j]);
    }
  }
  const int ow0 = q*14;
  const int nout = (q==3) ? 13 : 14;
  float* op = out + (((size_t)b*64 + oc)*55 + oh)*55 + ow0;
  for (int j=0;j<nout;++j) op[j] = fmaxf(acc[j], 0.f);
}

// =================== conv2: 64ch, 5x5, p2, 27x27 ===================
__global__ __launch_bounds__(TPB, 2) void conv2_k(
    const float* __restrict__ in, const float* __restrict__ w,
    const float* __restrict__ bias, float* __restrict__ out)
{
  const int CH = 4, ROWS = 31, STR = 36;
  __shared__ __align__(16) float s[CH*ROWS*STR];

  int octile = blockIdx.x % 24;
  int b      = blockIdx.x / 24;
  int oc_l   = threadIdx.x & 7;
  int oh     = threadIdx.x >> 3;
  int oc     = octile*8 + oc_l;

  float acc[27];
  #pragma unroll
  for (int j=0;j<27;++j) acc[j] = bias[oc];

  const float* ip = in + (size_t)b*64*27*27;

  for (int c0=0; c0<64; c0+=CH){
    __syncthreads();
    for (int l = threadIdx.x; l < CH*ROWS*STR; l += TPB){
      int ch  = l / (ROWS*STR);
      int rem = l % (ROWS*STR);
      int r   = rem / STR;
      int col = rem % STR;
      int ih = r - 2, iw = col - 2;
      float v = 0.f;
      if (ih >= 0 && ih < 27 && iw >= 0 && iw < 27)
        v = ip[((size_t)(c0+ch)*27 + ih)*27 + iw];
      s[l] = v;
    }
    __syncthreads();
    if (oh < 27){
      #pragma unroll
      for (int c=0;c<CH;++c){
        const float* wc = w + ((size_t)oc*64 + c0 + c)*25;
        #pragma unroll
        for (int kh=0;kh<5;++kh){
          const float* row = &s[c*ROWS*STR + (oh+kh)*STR];
          const float4* r4 = reinterpret_cast<const float4*>(row);
          float f[32];
          #pragma unroll
          for (int v=0; v<8; ++v){
            float4 qv = r4[v];
            f[v*4+0]=qv.x; f[v*4+1]=qv.y; f[v*4+2]=qv.z; f[v*4+3]=qv.w;
          }
          float wv[5];
          #pragma unroll
          for (int kw=0;kw<5;++kw) wv[kw] = wc[kh*5+kw];
          #pragma unroll
          for (int kw=0;kw<5;++kw)
            #pragma unroll
            for (int j=0;j<27;++j)
              acc[j] = fmaf(f[j+kw], wv[kw], acc[j]);
        }
      }
    }
  }
  if (oh < 27){
    float* op = out + (((size_t)b*192 + oc)*27 + oh)*27;
    #pragma unroll
    for (int j=0;j<27;++j) op[j] = fmaxf(acc[j], 0.f);
  }
}

// =================== 3x3 convs (conv3/4/5) ===================
template<int C,int O>
__global__ __launch_bounds__(TPB, 2) void conv3x3_k(
    const float* __restrict__ in, const float* __restrict__ w,
    const float* __restrict__ bias, float* __restrict__ out)
{
  const int CH = 16, ROWS = 15, STR = 20;
  __shared__ __align__(16) float s[CH*ROWS*STR];

  const int NT = O/16;
  int octile = blockIdx.x % NT;
  int b      = blockIdx.x / NT;
  int oc_l   = threadIdx.x & 15;
  int oh     = threadIdx.x >> 4;
  int oc     = octile*16 + oc_l;

  float acc[13];
  #pragma unroll
  for (int j=0;j<13;++j) acc[j] = bias[oc];

  const float* ip = in + (size_t)b*C*13*13;

  for (int c0=0; c0<C; c0+=CH){
    __syncthreads();
    for (int l = threadIdx.x; l < CH*ROWS*STR; l += TPB){
      int ch  = l / (ROWS*STR);
      int rem = l % (ROWS*STR);
      int r   = rem / STR;
      int col = rem % STR;
      int ih = r - 1, iw = col - 1;
      float v = 0.f;
      if (ih >= 0 && ih < 13 && iw >= 0 && iw < 13)
        v = ip[((size_t)(c0+ch)*13 + ih)*13 + iw];
      s[l] = v;
    }
    __syncthreads();
    if (oh < 13){
      #pragma unroll
      for (int c=0;c<CH;++c){
        const float* wc = w + ((size_t)oc*C + c0 + c)*9;
        float wv[9];
        #pragma unroll
        for (int qq=0;qq<9;++qq) wv[qq] = wc[qq];
        #pragma unroll
        for (int kh=0;kh<3;++kh){
          const float* row = &s[c*ROWS*STR + (oh+kh)*STR];
          const float4* r4 = reinterpret_cast<const float4*>(row);
          float f[16];
          #pragma unroll
          for (int v=0; v<4; ++v){
            float4 qv = r4[v];
            f[v*4+0]=qv.x; f[v*4+1]=qv.y; f[v*4+2]=qv.z; f[v*4+3]=qv.w;
          }
          #pragma unroll
          for (int kw=0;kw<3;++kw)
            #pragma unroll
            for (int j=0;j<13;++j)
              acc[j] = fmaf(f[j+kw], wv[kh*3+kw], acc[j]);
        }
      }
    }
  }
  if (oh < 13){
    float* op = out + (((size_t)b*O + oc)*13 + oh)*13;
    #pragma unroll
    for (int j=0;j<13;++j) op[j] = fmaxf(acc[j], 0.f);
  }
}

// ---------------- 3x3 stride-2 VALID maxpool ----------------
template<int HIN,int HOUT>
__global__ __launch_bounds__(TPB) void maxpool_k(
    const float* __restrict__ in, float* __restrict__ out, int nTotal)
{
  int idx = blockIdx.x*TPB + threadIdx.x;
  if (idx >= nTotal) return;
  int ow = idx % HOUT;
  int t  = idx / HOUT;
  int oh = t % HOUT;
  int ch = t / HOUT;
  const float* p = in + ((size_t)ch*HIN + oh*2)*HIN + ow*2;
  float m = -INFINITY;
  #pragma unroll
  for (int i=0;i<3;++i)
    #pragma unroll
    for (int j=0;j<3;++j)
      m = fmaxf(m, p[i*HIN + j]);
  out[idx] = m;
}

// ---------------- gate ----------------
__global__ __launch_bounds__(128) void gate_k(
    const float* __restrict__ feat, const float* __restrict__ gw1,
    const float* __restrict__ gb1,  const float* __restrict__ gw2,
    const float* __restrict__ gb2,  float* __restrict__ gates)
{
  int b = blockIdx.x;
  int tid = threadIdx.x;
  __shared__ float g[72];
  __shared__ float logits[8];
  if (tid < 72) {
    float acc = gb1[tid];
    const float* f = feat + (size_t)b*9216;
    for (int d=0; d<9216; ++d)
      acc = fmaf(f[d], gw1[(size_t)d*72 + tid], acc);
    g[tid] = fmaxf(acc, 0.f);
  }
  __syncthreads();
  if (tid < 8) {
    float acc = gb2[tid];
    for (int j=0;j<72;++j)
      acc = fmaf(g[j], gw2[(size_t)j*8 + tid], acc);
    logits[tid] = acc;
  }
  __syncthreads();
  if (tid == 0) {
    int i1 = 0; float v1 = logits[0];
    for (int e=1;e<8;++e) if (logits[e] > v1) { v1 = logits[e]; i1 = e; }
    int i2 = -1; float v2 = -INFINITY;
    for (int e=0;e<8;++e) { if (e==i1) continue; if (logits[e] > v2) { v2 = logits[e]; i2 = e; } }
    float z  = expf(v2 - v1);
    float w1 = 1.f / (1.f + z);
    float w2 = z   / (1.f + z);
    float* gr = gates + (size_t)b*8;
    for (int e=0;e<8;++e) gr[e] = 0.f;
    gr[i1] = w1;
    gr[i2] = w2;
  }
}

// ========== expert h1 as dense split-K GEMM (reads ew1 exactly once) ==========
// pass 1: part[ks][e][b][h] = sum_{d in chunk} feat[b][d] * ew1[e][d][h]
// grid (8e, 16ks, 2n); block 256 = 16x16; thread tile 4b x 9h; K chunk 576.
__global__ __launch_bounds__(256, 2) void eh1_part_k(
    const float* __restrict__ feat, const float* __restrict__ ew1,
    float* __restrict__ part)
{
  const int e  = blockIdx.x;
  const int ks = blockIdx.y;
  const int nb = blockIdx.z;
  const int h0 = nb*144;
  __shared__ __align__(16) float fs[64*33];     // feat tile 64x32 (pad 33)
  __shared__ __align__(16) float wsh[32*144];   // w tile 32x144
  const int tid = threadIdx.x;
  const int tx = tid & 15;
  const int ty = tid >> 4;
  float acc[4][9];
  #pragma unroll
  for (int i=0;i<4;++i)
    #pragma unroll
    for (int j=0;j<9;++j) acc[i][j]=0.f;
  const float* wbase = ew1 + (size_t)e*9216*288 + h0;
  for (int d0 = ks*576; d0 < ks*576+576; d0 += 32){
    __syncthreads();
    for (int l = tid; l < 512; l += 256){          // feat: 64 rows x 8 f4
      int r = l >> 3, c = l & 7;
      float4 v = *reinterpret_cast<const float4*>(feat + (size_t)r*9216 + d0 + c*4);
      float* dst = &fs[r*33 + c*4];
      dst[0]=v.x; dst[1]=v.y; dst[2]=v.z; dst[3]=v.w;
    }
    for (int l = tid; l < 1152; l += 256){         // w: 32 rows x 36 f4
      int r = l / 36, c = l % 36;
      *reinterpret_cast<float4*>(&wsh[r*144 + c*4]) =
        *reinterpret_cast<const float4*>(wbase + (size_t)(d0 + r)*288 + c*4);
    }
    __syncthreads();
    #pragma unroll
    for (int k=0;k<32;++k){
      float fv[4], wv[9];
      #pragma unroll
      for (int i=0;i<4;++i) fv[i] = fs[(ty*4+i)*33 + k];
      #pragma unroll
      for (int j=0;j<9;++j) wv[j] = wsh[k*144 + tx*9 + j];
      #pragma unroll
      for (int i=0;i<4;++i)
        #pragma unroll
        for (int j=0;j<9;++j)
          acc[i][j] = fmaf(fv[i], wv[j], acc[i][j]);
    }
  }
  float* pp = part + (size_t)(ks*8 + e)*64*288;
  #pragma unroll
  for (int i=0;i<4;++i)
    #pragma unroll
    for (int j=0;j<9;++j)
      pp[(ty*4+i)*288 + h0 + tx*9 + j] = acc[i][j];
}

// pass 2: h1 = relu(sum_ks part + bias)
__global__ __launch_bounds__(TPB) void eh1_reduce_k(
    const float* __restrict__ part, const float* __restrict__ eb1,
    float* __restrict__ h1)
{
  int idx = blockIdx.x*TPB + threadIdx.x;
  if (idx >= 8*64*288) return;
  int h = idx % 288;
  int e = idx / (64*288);
  float a = eb1[(size_t)e*288 + h];
  #pragma unroll
  for (int s=0;s<16;++s)
    a += part[(size_t)s*147456 + idx];
  h1[idx] = fmaxf(a, 0.f);
}

// ---------------- expert h2 / out (gated skip = exact) ----------------
__global__ __launch_bounds__(TPB) void expert_h2_k(
    const float* __restrict__ h1, const float* __restrict__ ew2,
    const float* __restrict__ eb2, const float* __restrict__ gates,
    float* __restrict__ h2)
{
  int idx = blockIdx.x*TPB + threadIdx.x;
  if (idx >= 8*64*144) return;
  int k = idx % 144;
  int t = idx / 144;
  int b = t % 64;
  int e = t / 64;
  if (gates[(size_t)b*8 + e] == 0.f) return;
  float acc = eb2[(size_t)e*144 + k];
  const float* h = h1 + ((size_t)e*64 + b)*288;
  const float* w = ew2 + (size_t)e*288*144 + k;
  for (int d=0; d<288; ++d)
    acc = fmaf(h[d], w[(size_t)d*144], acc);
  h2[idx] = fmaxf(acc, 0.f);
}

__global__ __launch_bounds__(TPB) void expert_out_k(
    const float* __restrict__ h2, const float* __restrict__ ew3,
    const float* __restrict__ eb3, const float* __restrict__ gates,
    float* __restrict__ out)
{
  int idx = blockIdx.x*TPB + threadIdx.x;
  if (idx >= 64*1000) return;
  int o = idx % 1000;
  int b = idx / 1000;
  float acc = 0.f;
  const float* gr = gates + (size_t)b*8;
  for (int e=0;e<8;++e){
    float ge = gr[e];
    if (ge == 0.f) continue;
    float a = eb3[(size_t)e*1000 + o];
    const float* h = h2 + ((size_t)e*64 + b)*144;
    const float* w = ew3 + (size_t)e*144*1000 + o;
    for (int k=0;k<144;++k)
      a = fmaf(h[k], w[(size_t)k*1000], a);
    acc = fmaf(ge, a, acc);
  }
  out[idx] = acc;
}

static inline int nblk(long long n){ return (int)((n + TPB - 1) / TPB); }

extern "C" void kernel_launch(void* const* d_in, const int* in_sizes, int n_in,
                              void* d_out, int out_size, void* d_ws, size_t ws_size,
                              hipStream_t stream)
{
  const float* x   = (const float*)d_in[0];
  const float* c1w = (const float*)d_in[1];  const float* c1b = (const float*)d_in[2];
  const float* c2w = (const float*)d_in[3];  const float* c2b = (const float*)d_in[4];
  const float* c3w = (const float*)d_in[5];  const float* c3b = (const float*)d_in[6];
  const float* c4w = (const float*)d_in[7];  const float* c4b = (const float*)d_in[8];
  const float* c5w = (const float*)d_in[9];  const float* c5b = (const float*)d_in[10];
  const float* gw1 = (const float*)d_in[11]; const float* gb1 = (const float*)d_in[12];
  const float* gw2 = (const float*)d_in[13]; const float* gb2 = (const float*)d_in[14];
  const float* ew1 = (const float*)d_in[15]; const float* eb1 = (const float*)d_in[16];
  const float* ew2 = (const float*)d_in[17]; const float* eb2 = (const float*)d_in[18];
  const float* ew3 = (const float*)d_in[19]; const float* eb3 = (const float*)d_in[20];
  float* out = (float*)d_out;

  const long long A_FLOATS = 12390400LL;
  const long long B_FLOATS = 2985984LL;
  float* A = (float*)d_ws;
  float* B = A + A_FLOATS;
  float* Cg = B + B_FLOATS;
  float* gates = Cg;
  float* h1    = Cg + 512;
  float* h2    = h1 + 147456;
  (void)ws_size; (void)in_sizes; (void)n_in; (void)out_size;

  const int B_ = 64;

  // conv1: x -> A [64,64,55,55]
  conv1_k<<<64*55, 256, 0, stream>>>(x, c1w, c1b, A);
  // pool1: A -> B [64,64,27,27]
  {
    long long n = (long long)B_*64*27*27;
    maxpool_k<55,27><<<nblk(n), TPB, 0, stream>>>(A, B, (int)n);
  }
  // conv2: B -> A [64,192,27,27]
  conv2_k<<<64*24, TPB, 0, stream>>>(B, c2w, c2b, A);
  // pool2: A -> B [64,192,13,13]
  {
    long long n = (long long)B_*192*13*13;
    maxpool_k<27,13><<<nblk(n), TPB, 0, stream>>>(A, B, (int)n);
  }
  // conv3: B -> A [64,384,13,13]
  conv3x3_k<192,384><<<64*24, TPB, 0, stream>>>(B, c3w, c3b, A);
  // conv4: A -> B [64,256,13,13]
  conv3x3_k<384,256><<<64*16, TPB, 0, stream>>>(A, c4w, c4b, B);
  // conv5: B -> A [64,256,13,13]
  conv3x3_k<256,256><<<64*16, TPB, 0, stream>>>(B, c5w, c5b, A);
  // pool3: A -> B = feat [64,9216]
  {
    long long n = (long long)B_*256*6*6;
    maxpool_k<13,6><<<nblk(n), TPB, 0, stream>>>(A, B, (int)n);
  }
  const float* feat = B;

  gate_k<<<B_, 128, 0, stream>>>(feat, gw1, gb1, gw2, gb2, gates);

  // experts: h1 dense split-K GEMM (partials in A, which is free now)
  float* part = A;
  eh1_part_k<<<dim3(8,16,2), 256, 0, stream>>>(feat, ew1, part);
  eh1_reduce_k<<<nblk(8LL*64*288), TPB, 0, stream>>>(part, eb1, h1);
  expert_h2_k<<<nblk(8LL*64*144), TPB, 0, stream>>>(h1, ew2, eb2, gates, h2);
  expert_out_k<<<nblk(64LL*1000), TPB, 0, stream>>>(h2, ew3, eb3, gates, out);
}

// Round 4
// 2847.142 us; speedup vs baseline: 5.6480x; 1.0747x over previous
//
#include <hip/hip_runtime.h>
#include <math.h>

#define TPB 256

// =================== weight transpose: w[O][C9] -> wT[C9][O] ===================
__global__ __launch_bounds__(TPB) void wtrans_k(
    const float* __restrict__ w, float* __restrict__ wT, int C9, int O)
{
  int idx = blockIdx.x*TPB + threadIdx.x;
  if (idx >= C9*O) return;
  int oc = idx % O;
  int c9 = idx / O;
  wT[idx] = w[(size_t)oc*C9 + c9];
}

// =================== conv1: oc-broadcast LDS scheme ===================
#define C1W 236
__global__ __launch_bounds__(256, 3) void conv1_k(
    const float* __restrict__ in, const float* __restrict__ w,
    const float* __restrict__ bias, float* __restrict__ out)
{
  __shared__ __align__(16) float s[33*C1W];
  const int oh = blockIdx.x % 55;
  const int b  = blockIdx.x / 55;
  const int oc = threadIdx.x & 63;
  const int q  = threadIdx.x >> 6;

  const int NF4 = 33*(C1W/4);
  for (int l = threadIdx.x; l < NF4; l += 256){
    int row = l / 59;
    int p4  = l % 59;
    int kh = row % 11, c = row / 11;
    int ih = oh*4 - 2 + kh;
    int iw0 = p4*4 - 4;
    float4 v = make_float4(0.f,0.f,0.f,0.f);
    if (ih >= 0 && ih < 224 && iw0 >= 0 && iw0 <= 220)
      v = *reinterpret_cast<const float4*>(in + ((size_t)(b*3 + c)*224 + ih)*224 + iw0);
    *reinterpret_cast<float4*>(&s[row*C1W + p4*4]) = v;
  }
  __syncthreads();

  float acc[14];
  float bb = bias[oc];
  #pragma unroll
  for (int j=0;j<14;++j) acc[j] = bb;
  const float* wp = w + (size_t)oc*363;
  const int base = q*56;

  #pragma unroll 1
  for (int c=0;c<3;++c){
    #pragma unroll
    for (int kh=0;kh<11;++kh){
      const float* srow = &s[(c*11+kh)*C1W + base];
      float f[68];
      #pragma unroll
      for (int v4=0; v4<17; ++v4){
        float4 t = *reinterpret_cast<const float4*>(srow + v4*4);
        f[v4*4+0]=t.x; f[v4*4+1]=t.y; f[v4*4+2]=t.z; f[v4*4+3]=t.w;
      }
      const float* wr = wp + c*121 + kh*11;
      float wv[11];
      #pragma unroll
      for (int kw=0;kw<11;++kw) wv[kw] = wr[kw];
      #pragma unroll
      for (int kw=0;kw<11;++kw)
        #pragma unroll
        for (int j=0;j<14;++j)
          acc[j] = fmaf(f[4*j + kw + 2], wv[kw], acc[j]);
    }
  }
  const int ow0 = q*14;
  const int nout = (q==3) ? 13 : 14;
  float* op = out + (((size_t)b*64 + oc)*55 + oh)*55 + ow0;
  for (int j=0;j<nout;++j) op[j] = fmaxf(acc[j], 0.f);
}

// =================== conv2 v2: LDS weights (wT), 2 oc/thread ===================
// grid (12 octiles x 64 b); block 256: oc_l = tid&7, oh = tid>>3 (<27 active).
// thread computes oc = base+oc_l and base+oc_l+8, full 27-wide row each.
__global__ __launch_bounds__(256, 4) void conv2_k(
    const float* __restrict__ in, const float* __restrict__ wT,
    const float* __restrict__ bias, float* __restrict__ out)
{
  const int CH = 4, ROWS = 31, STR = 36;
  __shared__ __align__(16) float si[CH*ROWS*STR];   // 4464 f
  __shared__ __align__(16) float sw[CH*25*16];      // 1600 f

  const int octile = blockIdx.x % 12;
  const int b      = blockIdx.x / 12;
  const int oc_l   = threadIdx.x & 7;
  const int oh     = threadIdx.x >> 3;
  const int obase  = octile*16;
  const int oc0    = obase + oc_l;

  float acc[2][27];
  float b0 = bias[oc0], b1 = bias[oc0+8];
  #pragma unroll
  for (int j=0;j<27;++j){ acc[0][j] = b0; acc[1][j] = b1; }

  const float* ip = in + (size_t)b*64*27*27;

  for (int c0=0; c0<64; c0+=CH){
    __syncthreads();
    for (int l = threadIdx.x; l < CH*ROWS*STR; l += 256){
      int ch  = l / (ROWS*STR);
      int rem = l % (ROWS*STR);
      int r   = rem / STR;
      int col = rem % STR;
      int ih = r - 2, iw = col - 2;
      float v = 0.f;
      if (ih >= 0 && ih < 27 && iw >= 0 && iw < 27)
        v = ip[((size_t)(c0+ch)*27 + ih)*27 + iw];
      si[l] = v;
    }
    for (int l = threadIdx.x; l < CH*25*16; l += 256){
      int ch   = l / 400;
      int rem  = l % 400;
      int tap  = rem / 16;
      int oc_i = rem % 16;
      sw[l] = wT[((size_t)(c0+ch)*25 + tap)*192 + obase + oc_i];
    }
    __syncthreads();
    if (oh < 27){
      #pragma unroll
      for (int c=0;c<CH;++c){
        #pragma unroll
        for (int kh=0;kh<5;++kh){
          const float* row = &si[c*ROWS*STR + (oh+kh)*STR];
          float f[32];
          #pragma unroll
          for (int v=0; v<8; ++v){
            float4 qv = *reinterpret_cast<const float4*>(row + v*4);
            f[v*4+0]=qv.x; f[v*4+1]=qv.y; f[v*4+2]=qv.z; f[v*4+3]=qv.w;
          }
          float wv[2][5];
          #pragma unroll
          for (int kw=0;kw<5;++kw){
            wv[0][kw] = sw[c*400 + (kh*5+kw)*16 + oc_l];
            wv[1][kw] = sw[c*400 + (kh*5+kw)*16 + oc_l + 8];
          }
          #pragma unroll
          for (int kw=0;kw<5;++kw)
            #pragma unroll
            for (int j=0;j<27;++j){
              acc[0][j] = fmaf(f[j+kw], wv[0][kw], acc[0][j]);
              acc[1][j] = fmaf(f[j+kw], wv[1][kw], acc[1][j]);
            }
        }
      }
    }
  }
  if (oh < 27){
    float* op0 = out + (((size_t)b*192 + oc0)*27 + oh)*27;
    float* op1 = op0 + (size_t)8*27*27;
    #pragma unroll
    for (int j=0;j<27;++j){
      op0[j] = fmaxf(acc[0][j], 0.f);
      op1[j] = fmaxf(acc[1][j], 0.f);
    }
  }
}

// =================== conv3/4/5 v2: LDS weights (wT), 2 oc/thread ===================
// grid ((O/32) octiles x 64 b); block 256: oc_l = tid&15, oh = tid>>4 (<13).
// thread computes oc = base+oc_l and base+oc_l+16, 13-wide row each.
template<int C,int O>
__global__ __launch_bounds__(256, 4) void conv3x3_k(
    const float* __restrict__ in, const float* __restrict__ wT,
    const float* __restrict__ bias, float* __restrict__ out)
{
  const int CH = 16, ROWS = 15, STR = 20;
  __shared__ __align__(16) float si[CH*ROWS*STR];   // 4800 f
  __shared__ __align__(16) float sw[CH*9*32];       // 4608 f

  const int NT = O/32;
  const int octile = blockIdx.x % NT;
  const int b      = blockIdx.x / NT;
  const int oc_l   = threadIdx.x & 15;
  const int oh     = threadIdx.x >> 4;
  const int obase  = octile*32;
  const int oc0    = obase + oc_l;

  float acc[2][13];
  float b0 = bias[oc0], b1 = bias[oc0+16];
  #pragma unroll
  for (int j=0;j<13;++j){ acc[0][j] = b0; acc[1][j] = b1; }

  const float* ip = in + (size_t)b*C*13*13;

  for (int c0=0; c0<C; c0+=CH){
    __syncthreads();
    for (int l = threadIdx.x; l < CH*ROWS*STR; l += 256){
      int ch  = l / (ROWS*STR);
      int rem = l % (ROWS*STR);
      int r   = rem / STR;
      int col = rem % STR;
      int ih = r - 1, iw = col - 1;
      float v = 0.f;
      if (ih >= 0 && ih < 13 && iw >= 0 && iw < 13)
        v = ip[((size_t)(c0+ch)*13 + ih)*13 + iw];
      si[l] = v;
    }
    for (int l = threadIdx.x; l < CH*9*32; l += 256){
      int ch   = l / 288;
      int rem  = l % 288;
      int tap  = rem / 32;
      int oc_i = rem % 32;
      sw[l] = wT[((size_t)(c0+ch)*9 + tap)*O + obase + oc_i];
    }
    __syncthreads();
    if (oh < 13){
      #pragma unroll 2
      for (int c=0;c<CH;++c){
        float wv[2][9];
        #pragma unroll
        for (int q=0;q<9;++q){
          wv[0][q] = sw[c*288 + q*32 + oc_l];
          wv[1][q] = sw[c*288 + q*32 + oc_l + 16];
        }
        #pragma unroll
        for (int kh=0;kh<3;++kh){
          const float* row = &si[c*ROWS*STR + (oh+kh)*STR];
          float f[16];
          #pragma unroll
          for (int v=0; v<4; ++v){
            float4 qv = *reinterpret_cast<const float4*>(row + v*4);
            f[v*4+0]=qv.x; f[v*4+1]=qv.y; f[v*4+2]=qv.z; f[v*4+3]=qv.w;
          }
          #pragma unroll
          for (int kw=0;kw<3;++kw)
            #pragma unroll
            for (int j=0;j<13;++j){
              acc[0][j] = fmaf(f[j+kw], wv[0][kh*3+kw], acc[0][j]);
              acc[1][j] = fmaf(f[j+kw], wv[1][kh*3+kw], acc[1][j]);
            }
        }
      }
    }
  }
  if (oh < 13){
    float* op0 = out + (((size_t)b*O + oc0)*13 + oh)*13;
    float* op1 = op0 + (size_t)16*13*13;
    #pragma unroll
    for (int j=0;j<13;++j){
      op0[j] = fmaxf(acc[0][j], 0.f);
      op1[j] = fmaxf(acc[1][j], 0.f);
    }
  }
}

// ---------------- 3x3 stride-2 VALID maxpool ----------------
template<int HIN,int HOUT>
__global__ __launch_bounds__(TPB) void maxpool_k(
    const float* __restrict__ in, float* __restrict__ out, int nTotal)
{
  int idx = blockIdx.x*TPB + threadIdx.x;
  if (idx >= nTotal) return;
  int ow = idx % HOUT;
  int t  = idx / HOUT;
  int oh = t % HOUT;
  int ch = t / HOUT;
  const float* p = in + ((size_t)ch*HIN + oh*2)*HIN + ow*2;
  float m = -INFINITY;
  #pragma unroll
  for (int i=0;i<3;++i)
    #pragma unroll
    for (int j=0;j<3;++j)
      m = fmaxf(m, p[i*HIN + j]);
  out[idx] = m;
}

// ---------------- gate ----------------
__global__ __launch_bounds__(128) void gate_k(
    const float* __restrict__ feat, const float* __restrict__ gw1,
    const float* __restrict__ gb1,  const float* __restrict__ gw2,
    const float* __restrict__ gb2,  float* __restrict__ gates)
{
  int b = blockIdx.x;
  int tid = threadIdx.x;
  __shared__ float g[72];
  __shared__ float logits[8];
  if (tid < 72) {
    float acc = gb1[tid];
    const float* f = feat + (size_t)b*9216;
    for (int d=0; d<9216; ++d)
      acc = fmaf(f[d], gw1[(size_t)d*72 + tid], acc);
    g[tid] = fmaxf(acc, 0.f);
  }
  __syncthreads();
  if (tid < 8) {
    float acc = gb2[tid];
    for (int j=0;j<72;++j)
      acc = fmaf(g[j], gw2[(size_t)j*8 + tid], acc);
    logits[tid] = acc;
  }
  __syncthreads();
  if (tid == 0) {
    int i1 = 0; float v1 = logits[0];
    for (int e=1;e<8;++e) if (logits[e] > v1) { v1 = logits[e]; i1 = e; }
    int i2 = -1; float v2 = -INFINITY;
    for (int e=0;e<8;++e) { if (e==i1) continue; if (logits[e] > v2) { v2 = logits[e]; i2 = e; } }
    float z  = expf(v2 - v1);
    float w1 = 1.f / (1.f + z);
    float w2 = z   / (1.f + z);
    float* gr = gates + (size_t)b*8;
    for (int e=0;e<8;++e) gr[e] = 0.f;
    gr[i1] = w1;
    gr[i2] = w2;
  }
}

// ========== expert h1 dense split-K GEMM ==========
__global__ __launch_bounds__(256, 2) void eh1_part_k(
    const float* __restrict__ feat, const float* __restrict__ ew1,
    float* __restrict__ part)
{
  const int e  = blockIdx.x;
  const int ks = blockIdx.y;
  const int nb = blockIdx.z;
  const int h0 = nb*144;
  __shared__ __align__(16) float fs[64*33];
  __shared__ __align__(16) float wsh[32*144];
  const int tid = threadIdx.x;
  const int tx = tid & 15;
  const int ty = tid >> 4;
  float acc[4][9];
  #pragma unroll
  for (int i=0;i<4;++i)
    #pragma unroll
    for (int j=0;j<9;++j) acc[i][j]=0.f;
  const float* wbase = ew1 + (size_t)e*9216*288 + h0;
  for (int d0 = ks*576; d0 < ks*576+576; d0 += 32){
    __syncthreads();
    for (int l = tid; l < 512; l += 256){
      int r = l >> 3, c = l & 7;
      float4 v = *reinterpret_cast<const float4*>(feat + (size_t)r*9216 + d0 + c*4);
      float* dst = &fs[r*33 + c*4];
      dst[0]=v.x; dst[1]=v.y; dst[2]=v.z; dst[3]=v.w;
    }
    for (int l = tid; l < 1152; l += 256){
      int r = l / 36, c = l % 36;
      *reinterpret_cast<float4*>(&wsh[r*144 + c*4]) =
        *reinterpret_cast<const float4*>(wbase + (size_t)(d0 + r)*288 + c*4);
    }
    __syncthreads();
    #pragma unroll
    for (int k=0;k<32;++k){
      float fv[4], wv[9];
      #pragma unroll
      for (int i=0;i<4;++i) fv[i] = fs[(ty*4+i)*33 + k];
      #pragma unroll
      for (int j=0;j<9;++j) wv[j] = wsh[k*144 + tx*9 + j];
      #pragma unroll
      for (int i=0;i<4;++i)
        #pragma unroll
        for (int j=0;j<9;++j)
          acc[i][j] = fmaf(fv[i], wv[j], acc[i][j]);
    }
  }
  float* pp = part + (size_t)(ks*8 + e)*64*288;
  #pragma unroll
  for (int i=0;i<4;++i)
    #pragma unroll
    for (int j=0;j<9;++j)
      pp[(ty*4+i)*288 + h0 + tx*9 + j] = acc[i][j];
}

__global__ __launch_bounds__(TPB) void eh1_reduce_k(
    const float* __restrict__ part, const float* __restrict__ eb1,
    float* __restrict__ h1)
{
  int idx = blockIdx.x*TPB + threadIdx.x;
  if (idx >= 8*64*288) return;
  int h = idx % 288;
  int e = idx / (64*288);
  float a = eb1[(size_t)e*288 + h];
  #pragma unroll
  for (int s=0;s<16;++s)
    a += part[(size_t)s*147456 + idx];
  h1[idx] = fmaxf(a, 0.f);
}

// ---------------- expert h2 / out ----------------
__global__ __launch_bounds__(TPB) void expert_h2_k(
    const float* __restrict__ h1, const float* __restrict__ ew2,
    const float* __restrict__ eb2, const float* __restrict__ gates,
    float* __restrict__ h2)
{
  int idx = blockIdx.x*TPB + threadIdx.x;
  if (idx >= 8*64*144) return;
  int k = idx % 144;
  int t = idx / 144;
  int b = t % 64;
  int e = t / 64;
  if (gates[(size_t)b*8 + e] == 0.f) return;
  float acc = eb2[(size_t)e*144 + k];
  const float* h = h1 + ((size_t)e*64 + b)*288;
  const float* w = ew2 + (size_t)e*288*144 + k;
  for (int d=0; d<288; ++d)
    acc = fmaf(h[d], w[(size_t)d*144], acc);
  h2[idx] = fmaxf(acc, 0.f);
}

__global__ __launch_bounds__(TPB) void expert_out_k(
    const float* __restrict__ h2, const float* __restrict__ ew3,
    const float* __restrict__ eb3, const float* __restrict__ gates,
    float* __restrict__ out)
{
  int idx = blockIdx.x*TPB + threadIdx.x;
  if (idx >= 64*1000) return;
  int o = idx % 1000;
  int b = idx / 1000;
  float acc = 0.f;
  const float* gr = gates + (size_t)b*8;
  for (int e=0;e<8;++e){
    float ge = gr[e];
    if (ge == 0.f) continue;
    float a = eb3[(size_t)e*1000 + o];
    const float* h = h2 + ((size_t)e*64 + b)*144;
    const float* w = ew3 + (size_t)e*144*1000 + o;
    for (int k=0;k<144;++k)
      a = fmaf(h[k], w[(size_t)k*1000], a);
    acc = fmaf(ge, a, acc);
  }
  out[idx] = acc;
}

static inline int nblk(long long n){ return (int)((n + TPB - 1) / TPB); }

extern "C" void kernel_launch(void* const* d_in, const int* in_sizes, int n_in,
                              void* d_out, int out_size, void* d_ws, size_t ws_size,
                              hipStream_t stream)
{
  const float* x   = (const float*)d_in[0];
  const float* c1w = (const float*)d_in[1];  const float* c1b = (const float*)d_in[2];
  const float* c2w = (const float*)d_in[3];  const float* c2b = (const float*)d_in[4];
  const float* c3w = (const float*)d_in[5];  const float* c3b = (const float*)d_in[6];
  const float* c4w = (const float*)d_in[7];  const float* c4b = (const float*)d_in[8];
  const float* c5w = (const float*)d_in[9];  const float* c5b = (const float*)d_in[10];
  const float* gw1 = (const float*)d_in[11]; const float* gb1 = (const float*)d_in[12];
  const float* gw2 = (const float*)d_in[13]; const float* gb2 = (const float*)d_in[14];
  const float* ew1 = (const float*)d_in[15]; const float* eb1 = (const float*)d_in[16];
  const float* ew2 = (const float*)d_in[17]; const float* eb2 = (const float*)d_in[18];
  const float* ew3 = (const float*)d_in[19]; const float* eb3 = (const float*)d_in[20];
  float* out = (float*)d_out;

  const long long A_FLOATS = 12390400LL;
  const long long B_FLOATS = 2985984LL;
  float* A = (float*)d_ws;
  float* B = A + A_FLOATS;
  float* Cg = B + B_FLOATS;
  float* gates = Cg;
  float* h1    = Cg + 512;
  float* h2    = h1 + 147456;
  // transposed weights live in the tail of A (dead after pool1)
  float* WT2 = A +  9000000;   // 307,200
  float* WT3 = A +  9400000;   // 663,552
  float* WT4 = A + 10100000;   // 884,736
  float* WT5 = A + 11000000;   // 589,824  (ends 11,589,824 < 12,390,400)
  (void)ws_size; (void)in_sizes; (void)n_in; (void)out_size;

  const int B_ = 64;

  // conv1: x -> A [64,64,55,55]
  conv1_k<<<64*55, 256, 0, stream>>>(x, c1w, c1b, A);
  // pool1: A -> B [64,64,27,27]
  {
    long long n = (long long)B_*64*27*27;
    maxpool_k<55,27><<<nblk(n), TPB, 0, stream>>>(A, B, (int)n);
  }
  // weight transposes into A tail (A is dead now)
  wtrans_k<<<nblk(1600LL*192), TPB, 0, stream>>>(c2w, WT2, 1600, 192);
  wtrans_k<<<nblk(1728LL*384), TPB, 0, stream>>>(c3w, WT3, 1728, 384);
  wtrans_k<<<nblk(3456LL*256), TPB, 0, stream>>>(c4w, WT4, 3456, 256);
  wtrans_k<<<nblk(2304LL*256), TPB, 0, stream>>>(c5w, WT5, 2304, 256);

  // conv2: B -> A [64,192,27,27]
  conv2_k<<<64*12, 256, 0, stream>>>(B, WT2, c2b, A);
  // pool2: A -> B [64,192,13,13]
  {
    long long n = (long long)B_*192*13*13;
    maxpool_k<27,13><<<nblk(n), TPB, 0, stream>>>(A, B, (int)n);
  }
  // conv3: B -> A [64,384,13,13]
  conv3x3_k<192,384><<<64*12, 256, 0, stream>>>(B, WT3, c3b, A);
  // conv4: A -> B [64,256,13,13]
  conv3x3_k<384,256><<<64*8, 256, 0, stream>>>(A, WT4, c4b, B);
  // conv5: B -> A [64,256,13,13]
  conv3x3_k<256,256><<<64*8, 256, 0, stream>>>(B, WT5, c5b, A);
  // pool3: A -> B = feat [64,9216]
  {
    long long n = (long long)B_*256*6*6;
    maxpool_k<13,6><<<nblk(n), TPB, 0, stream>>>(A, B, (int)n);
  }
  const float* feat = B;

  gate_k<<<B_, 128, 0, stream>>>(feat, gw1, gb1, gw2, gb2, gates);

  float* part = A;
  eh1_part_k<<<dim3(8,16,2), 256, 0, stream>>>(feat, ew1, part);
  eh1_reduce_k<<<nblk(8LL*64*288), TPB, 0, stream>>>(part, eb1, h1);
  expert_h2_k<<<nblk(8LL*64*144), TPB, 0, stream>>>(h1, ew2, eb2, gates, h2);
  expert_out_k<<<nblk(64LL*1000), TPB, 0, stream>>>(h2, ew3, eb3, gates, out);
}

// Round 5
// 2518.776 us; speedup vs baseline: 6.3843x; 1.1304x over previous
//
#include <hip/hip_runtime.h>
#include <math.h>

#define TPB 256

// =================== weight transpose: w[O][C9] -> wT[C9][O] ===================
__global__ __launch_bounds__(TPB) void wtrans_k(
    const float* __restrict__ w, float* __restrict__ wT, int C9, int O)
{
  int idx = blockIdx.x*TPB + threadIdx.x;
  if (idx >= C9*O) return;
  int oc = idx % O;
  int c9 = idx / O;
  wT[idx] = w[(size_t)oc*C9 + c9];
}

// =================== conv1: oc-broadcast LDS scheme ===================
#define C1W 236
__global__ __launch_bounds__(256, 3) void conv1_k(
    const float* __restrict__ in, const float* __restrict__ w,
    const float* __restrict__ bias, float* __restrict__ out)
{
  __shared__ __align__(16) float s[33*C1W];
  const int oh = blockIdx.x % 55;
  const int b  = blockIdx.x / 55;
  const int oc = threadIdx.x & 63;
  const int q  = threadIdx.x >> 6;

  const int NF4 = 33*(C1W/4);
  for (int l = threadIdx.x; l < NF4; l += 256){
    int row = l / 59;
    int p4  = l % 59;
    int kh = row % 11, c = row / 11;
    int ih = oh*4 - 2 + kh;
    int iw0 = p4*4 - 4;
    float4 v = make_float4(0.f,0.f,0.f,0.f);
    if (ih >= 0 && ih < 224 && iw0 >= 0 && iw0 <= 220)
      v = *reinterpret_cast<const float4*>(in + ((size_t)(b*3 + c)*224 + ih)*224 + iw0);
    *reinterpret_cast<float4*>(&s[row*C1W + p4*4]) = v;
  }
  __syncthreads();

  float acc[14];
  float bb = bias[oc];
  #pragma unroll
  for (int j=0;j<14;++j) acc[j] = bb;
  const float* wp = w + (size_t)oc*363;
  const int base = q*56;

  #pragma unroll 1
  for (int c=0;c<3;++c){
    #pragma unroll
    for (int kh=0;kh<11;++kh){
      const float* srow = &s[(c*11+kh)*C1W + base];
      float f[68];
      #pragma unroll
      for (int v4=0; v4<17; ++v4){
        float4 t = *reinterpret_cast<const float4*>(srow + v4*4);
        f[v4*4+0]=t.x; f[v4*4+1]=t.y; f[v4*4+2]=t.z; f[v4*4+3]=t.w;
      }
      const float* wr = wp + c*121 + kh*11;
      float wv[11];
      #pragma unroll
      for (int kw=0;kw<11;++kw) wv[kw] = wr[kw];
      #pragma unroll
      for (int kw=0;kw<11;++kw)
        #pragma unroll
        for (int j=0;j<14;++j)
          acc[j] = fmaf(f[4*j + kw + 2], wv[kw], acc[j]);
    }
  }
  const int ow0 = q*14;
  const int nout = (q==3) ? 13 : 14;
  float* op = out + (((size_t)b*64 + oc)*55 + oh)*55 + ow0;
  for (int j=0;j<nout;++j) op[j] = fmaxf(acc[j], 0.f);
}

// =================== conv2 v3: 1 oc/thread + LDS weights ===================
// grid (24 octiles x 64 b); block 256: oc_l = tid&7, oh = tid>>3 (<27 active).
// si: 4ch padded 31x36 input; sw: 4ch x 25 taps x 8 ocs (coalesced wT loads).
__global__ __launch_bounds__(256, 3) void conv2_k(
    const float* __restrict__ in, const float* __restrict__ wT,
    const float* __restrict__ bias, float* __restrict__ out)
{
  const int CH = 4, ROWS = 31, STR = 36;
  __shared__ __align__(16) float si[CH*ROWS*STR];   // 4464 f
  __shared__ __align__(16) float sw[CH*25*8];       // 800 f

  const int octile = blockIdx.x % 24;
  const int b      = blockIdx.x / 24;
  const int oc_l   = threadIdx.x & 7;
  const int oh     = threadIdx.x >> 3;
  const int obase  = octile*8;
  const int oc     = obase + oc_l;

  float acc[27];
  float bb = bias[oc];
  #pragma unroll
  for (int j=0;j<27;++j) acc[j] = bb;

  const float* ip = in + (size_t)b*64*27*27;

  for (int c0=0; c0<64; c0+=CH){
    __syncthreads();
    for (int l = threadIdx.x; l < CH*ROWS*STR; l += 256){
      int ch  = l / (ROWS*STR);
      int rem = l % (ROWS*STR);
      int r   = rem / STR;
      int col = rem % STR;
      int ih = r - 2, iw = col - 2;
      float v = 0.f;
      if (ih >= 0 && ih < 27 && iw >= 0 && iw < 27)
        v = ip[((size_t)(c0+ch)*27 + ih)*27 + iw];
      si[l] = v;
    }
    for (int l = threadIdx.x; l < CH*25*8; l += 256){
      int ch   = l / 200;
      int rem  = l % 200;
      int tap  = rem / 8;
      int oc_i = rem % 8;
      sw[l] = wT[((size_t)(c0+ch)*25 + tap)*192 + obase + oc_i];
    }
    __syncthreads();
    if (oh < 27){
      #pragma unroll
      for (int c=0;c<CH;++c){
        #pragma unroll
        for (int kh=0;kh<5;++kh){
          const float* row = &si[c*ROWS*STR + (oh+kh)*STR];
          float f[32];
          #pragma unroll
          for (int v=0; v<8; ++v){
            float4 qv = *reinterpret_cast<const float4*>(row + v*4);
            f[v*4+0]=qv.x; f[v*4+1]=qv.y; f[v*4+2]=qv.z; f[v*4+3]=qv.w;
          }
          float wv[5];
          #pragma unroll
          for (int kw=0;kw<5;++kw)
            wv[kw] = sw[c*200 + (kh*5+kw)*8 + oc_l];
          #pragma unroll
          for (int kw=0;kw<5;++kw)
            #pragma unroll
            for (int j=0;j<27;++j)
              acc[j] = fmaf(f[j+kw], wv[kw], acc[j]);
        }
      }
    }
  }
  if (oh < 27){
    float* op = out + (((size_t)b*192 + oc)*27 + oh)*27;
    #pragma unroll
    for (int j=0;j<27;++j)
      op[j] = fmaxf(acc[j], 0.f);
  }
}

// =================== conv3/4/5 v2: LDS weights (wT), 2 oc/thread ===================
template<int C,int O>
__global__ __launch_bounds__(256, 4) void conv3x3_k(
    const float* __restrict__ in, const float* __restrict__ wT,
    const float* __restrict__ bias, float* __restrict__ out)
{
  const int CH = 16, ROWS = 15, STR = 20;
  __shared__ __align__(16) float si[CH*ROWS*STR];   // 4800 f
  __shared__ __align__(16) float sw[CH*9*32];       // 4608 f

  const int NT = O/32;
  const int octile = blockIdx.x % NT;
  const int b      = blockIdx.x / NT;
  const int oc_l   = threadIdx.x & 15;
  const int oh     = threadIdx.x >> 4;
  const int obase  = octile*32;
  const int oc0    = obase + oc_l;

  float acc[2][13];
  float b0 = bias[oc0], b1 = bias[oc0+16];
  #pragma unroll
  for (int j=0;j<13;++j){ acc[0][j] = b0; acc[1][j] = b1; }

  const float* ip = in + (size_t)b*C*13*13;

  for (int c0=0; c0<C; c0+=CH){
    __syncthreads();
    for (int l = threadIdx.x; l < CH*ROWS*STR; l += 256){
      int ch  = l / (ROWS*STR);
      int rem = l % (ROWS*STR);
      int r   = rem / STR;
      int col = rem % STR;
      int ih = r - 1, iw = col - 1;
      float v = 0.f;
      if (ih >= 0 && ih < 13 && iw >= 0 && iw < 13)
        v = ip[((size_t)(c0+ch)*13 + ih)*13 + iw];
      si[l] = v;
    }
    for (int l = threadIdx.x; l < CH*9*32; l += 256){
      int ch   = l / 288;
      int rem  = l % 288;
      int tap  = rem / 32;
      int oc_i = rem % 32;
      sw[l] = wT[((size_t)(c0+ch)*9 + tap)*O + obase + oc_i];
    }
    __syncthreads();
    if (oh < 13){
      #pragma unroll 2
      for (int c=0;c<CH;++c){
        float wv[2][9];
        #pragma unroll
        for (int q=0;q<9;++q){
          wv[0][q] = sw[c*288 + q*32 + oc_l];
          wv[1][q] = sw[c*288 + q*32 + oc_l + 16];
        }
        #pragma unroll
        for (int kh=0;kh<3;++kh){
          const float* row = &si[c*ROWS*STR + (oh+kh)*STR];
          float f[16];
          #pragma unroll
          for (int v=0; v<4; ++v){
            float4 qv = *reinterpret_cast<const float4*>(row + v*4);
            f[v*4+0]=qv.x; f[v*4+1]=qv.y; f[v*4+2]=qv.z; f[v*4+3]=qv.w;
          }
          #pragma unroll
          for (int kw=0;kw<3;++kw)
            #pragma unroll
            for (int j=0;j<13;++j){
              acc[0][j] = fmaf(f[j+kw], wv[0][kh*3+kw], acc[0][j]);
              acc[1][j] = fmaf(f[j+kw], wv[1][kh*3+kw], acc[1][j]);
            }
        }
      }
    }
  }
  if (oh < 13){
    float* op0 = out + (((size_t)b*O + oc0)*13 + oh)*13;
    float* op1 = op0 + (size_t)16*13*13;
    #pragma unroll
    for (int j=0;j<13;++j){
      op0[j] = fmaxf(acc[0][j], 0.f);
      op1[j] = fmaxf(acc[1][j], 0.f);
    }
  }
}

// ---------------- 3x3 stride-2 VALID maxpool ----------------
template<int HIN,int HOUT>
__global__ __launch_bounds__(TPB) void maxpool_k(
    const float* __restrict__ in, float* __restrict__ out, int nTotal)
{
  int idx = blockIdx.x*TPB + threadIdx.x;
  if (idx >= nTotal) return;
  int ow = idx % HOUT;
  int t  = idx / HOUT;
  int oh = t % HOUT;
  int ch = t / HOUT;
  const float* p = in + ((size_t)ch*HIN + oh*2)*HIN + ow*2;
  float m = -INFINITY;
  #pragma unroll
  for (int i=0;i<3;++i)
    #pragma unroll
    for (int j=0;j<3;++j)
      m = fmaxf(m, p[i*HIN + j]);
  out[idx] = m;
}

// ---------------- gate ----------------
__global__ __launch_bounds__(128) void gate_k(
    const float* __restrict__ feat, const float* __restrict__ gw1,
    const float* __restrict__ gb1,  const float* __restrict__ gw2,
    const float* __restrict__ gb2,  float* __restrict__ gates)
{
  int b = blockIdx.x;
  int tid = threadIdx.x;
  __shared__ float g[72];
  __shared__ float logits[8];
  if (tid < 72) {
    float acc = gb1[tid];
    const float* f = feat + (size_t)b*9216;
    for (int d=0; d<9216; ++d)
      acc = fmaf(f[d], gw1[(size_t)d*72 + tid], acc);
    g[tid] = fmaxf(acc, 0.f);
  }
  __syncthreads();
  if (tid < 8) {
    float acc = gb2[tid];
    for (int j=0;j<72;++j)
      acc = fmaf(g[j], gw2[(size_t)j*8 + tid], acc);
    logits[tid] = acc;
  }
  __syncthreads();
  if (tid == 0) {
    int i1 = 0; float v1 = logits[0];
    for (int e=1;e<8;++e) if (logits[e] > v1) { v1 = logits[e]; i1 = e; }
    int i2 = -1; float v2 = -INFINITY;
    for (int e=0;e<8;++e) { if (e==i1) continue; if (logits[e] > v2) { v2 = logits[e]; i2 = e; } }
    float z  = expf(v2 - v1);
    float w1 = 1.f / (1.f + z);
    float w2 = z   / (1.f + z);
    float* gr = gates + (size_t)b*8;
    for (int e=0;e<8;++e) gr[e] = 0.f;
    gr[i1] = w1;
    gr[i2] = w2;
  }
}

// ========== expert h1 dense split-K GEMM ==========
__global__ __launch_bounds__(256, 2) void eh1_part_k(
    const float* __restrict__ feat, const float* __restrict__ ew1,
    float* __restrict__ part)
{
  const int e  = blockIdx.x;
  const int ks = blockIdx.y;
  const int nb = blockIdx.z;
  const int h0 = nb*144;
  __shared__ __align__(16) float fs[64*33];
  __shared__ __align__(16) float wsh[32*144];
  const int tid = threadIdx.x;
  const int tx = tid & 15;
  const int ty = tid >> 4;
  float acc[4][9];
  #pragma unroll
  for (int i=0;i<4;++i)
    #pragma unroll
    for (int j=0;j<9;++j) acc[i][j]=0.f;
  const float* wbase = ew1 + (size_t)e*9216*288 + h0;
  for (int d0 = ks*576; d0 < ks*576+576; d0 += 32){
    __syncthreads();
    for (int l = tid; l < 512; l += 256){
      int r = l >> 3, c = l & 7;
      float4 v = *reinterpret_cast<const float4*>(feat + (size_t)r*9216 + d0 + c*4);
      float* dst = &fs[r*33 + c*4];
      dst[0]=v.x; dst[1]=v.y; dst[2]=v.z; dst[3]=v.w;
    }
    for (int l = tid; l < 1152; l += 256){
      int r = l / 36, c = l % 36;
      *reinterpret_cast<float4*>(&wsh[r*144 + c*4]) =
        *reinterpret_cast<const float4*>(wbase + (size_t)(d0 + r)*288 + c*4);
    }
    __syncthreads();
    #pragma unroll
    for (int k=0;k<32;++k){
      float fv[4], wv[9];
      #pragma unroll
      for (int i=0;i<4;++i) fv[i] = fs[(ty*4+i)*33 + k];
      #pragma unroll
      for (int j=0;j<9;++j) wv[j] = wsh[k*144 + tx*9 + j];
      #pragma unroll
      for (int i=0;i<4;++i)
        #pragma unroll
        for (int j=0;j<9;++j)
          acc[i][j] = fmaf(fv[i], wv[j], acc[i][j]);
    }
  }
  float* pp = part + (size_t)(ks*8 + e)*64*288;
  #pragma unroll
  for (int i=0;i<4;++i)
    #pragma unroll
    for (int j=0;j<9;++j)
      pp[(ty*4+i)*288 + h0 + tx*9 + j] = acc[i][j];
}

__global__ __launch_bounds__(TPB) void eh1_reduce_k(
    const float* __restrict__ part, const float* __restrict__ eb1,
    float* __restrict__ h1)
{
  int idx = blockIdx.x*TPB + threadIdx.x;
  if (idx >= 8*64*288) return;
  int h = idx % 288;
  int e = idx / (64*288);
  float a = eb1[(size_t)e*288 + h];
  #pragma unroll
  for (int s=0;s<16;++s)
    a += part[(size_t)s*147456 + idx];
  h1[idx] = fmaxf(a, 0.f);
}

// ---------------- expert h2 / out ----------------
__global__ __launch_bounds__(TPB) void expert_h2_k(
    const float* __restrict__ h1, const float* __restrict__ ew2,
    const float* __restrict__ eb2, const float* __restrict__ gates,
    float* __restrict__ h2)
{
  int idx = blockIdx.x*TPB + threadIdx.x;
  if (idx >= 8*64*144) return;
  int k = idx % 144;
  int t = idx / 144;
  int b = t % 64;
  int e = t / 64;
  if (gates[(size_t)b*8 + e] == 0.f) return;
  float acc = eb2[(size_t)e*144 + k];
  const float* h = h1 + ((size_t)e*64 + b)*288;
  const float* w = ew2 + (size_t)e*288*144 + k;
  for (int d=0; d<288; ++d)
    acc = fmaf(h[d], w[(size_t)d*144], acc);
  h2[idx] = fmaxf(acc, 0.f);
}

__global__ __launch_bounds__(TPB) void expert_out_k(
    const float* __restrict__ h2, const float* __restrict__ ew3,
    const float* __restrict__ eb3, const float* __restrict__ gates,
    float* __restrict__ out)
{
  int idx = blockIdx.x*TPB + threadIdx.x;
  if (idx >= 64*1000) return;
  int o = idx % 1000;
  int b = idx / 1000;
  float acc = 0.f;
  const float* gr = gates + (size_t)b*8;
  for (int e=0;e<8;++e){
    float ge = gr[e];
    if (ge == 0.f) continue;
    float a = eb3[(size_t)e*1000 + o];
    const float* h = h2 + ((size_t)e*64 + b)*144;
    const float* w = ew3 + (size_t)e*144*1000 + o;
    for (int k=0;k<144;++k)
      a = fmaf(h[k], w[(size_t)k*1000], a);
    acc = fmaf(ge, a, acc);
  }
  out[idx] = acc;
}

static inline int nblk(long long n){ return (int)((n + TPB - 1) / TPB); }

extern "C" void kernel_launch(void* const* d_in, const int* in_sizes, int n_in,
                              void* d_out, int out_size, void* d_ws, size_t ws_size,
                              hipStream_t stream)
{
  const float* x   = (const float*)d_in[0];
  const float* c1w = (const float*)d_in[1];  const float* c1b = (const float*)d_in[2];
  const float* c2w = (const float*)d_in[3];  const float* c2b = (const float*)d_in[4];
  const float* c3w = (const float*)d_in[5];  const float* c3b = (const float*)d_in[6];
  const float* c4w = (const float*)d_in[7];  const float* c4b = (const float*)d_in[8];
  const float* c5w = (const float*)d_in[9];  const float* c5b = (const float*)d_in[10];
  const float* gw1 = (const float*)d_in[11]; const float* gb1 = (const float*)d_in[12];
  const float* gw2 = (const float*)d_in[13]; const float* gb2 = (const float*)d_in[14];
  const float* ew1 = (const float*)d_in[15]; const float* eb1 = (const float*)d_in[16];
  const float* ew2 = (const float*)d_in[17]; const float* eb2 = (const float*)d_in[18];
  const float* ew3 = (const float*)d_in[19]; const float* eb3 = (const float*)d_in[20];
  float* out = (float*)d_out;

  const long long A_FLOATS = 12390400LL;
  const long long B_FLOATS = 2985984LL;
  float* A = (float*)d_ws;
  float* B = A + A_FLOATS;
  float* Cg = B + B_FLOATS;
  float* gates = Cg;
  float* h1    = Cg + 512;
  float* h2    = h1 + 147456;
  // transposed weights live in the tail of A (dead after pool1)
  float* WT2 = A +  9000000;   // 307,200
  float* WT3 = A +  9400000;   // 663,552
  float* WT4 = A + 10100000;   // 884,736
  float* WT5 = A + 11000000;   // 589,824  (ends 11,589,824 < 12,390,400)
  (void)ws_size; (void)in_sizes; (void)n_in; (void)out_size;

  const int B_ = 64;

  // conv1: x -> A [64,64,55,55]
  conv1_k<<<64*55, 256, 0, stream>>>(x, c1w, c1b, A);
  // pool1: A -> B [64,64,27,27]
  {
    long long n = (long long)B_*64*27*27;
    maxpool_k<55,27><<<nblk(n), TPB, 0, stream>>>(A, B, (int)n);
  }
  // weight transposes into A tail (A is dead now)
  wtrans_k<<<nblk(1600LL*192), TPB, 0, stream>>>(c2w, WT2, 1600, 192);
  wtrans_k<<<nblk(1728LL*384), TPB, 0, stream>>>(c3w, WT3, 1728, 384);
  wtrans_k<<<nblk(3456LL*256), TPB, 0, stream>>>(c4w, WT4, 3456, 256);
  wtrans_k<<<nblk(2304LL*256), TPB, 0, stream>>>(c5w, WT5, 2304, 256);

  // conv2: B -> A [64,192,27,27]
  conv2_k<<<64*24, 256, 0, stream>>>(B, WT2, c2b, A);
  // pool2: A -> B [64,192,13,13]
  {
    long long n = (long long)B_*192*13*13;
    maxpool_k<27,13><<<nblk(n), TPB, 0, stream>>>(A, B, (int)n);
  }
  // conv3: B -> A [64,384,13,13]
  conv3x3_k<192,384><<<64*12, 256, 0, stream>>>(B, WT3, c3b, A);
  // conv4: A -> B [64,256,13,13]
  conv3x3_k<384,256><<<64*8, 256, 0, stream>>>(A, WT4, c4b, B);
  // conv5: B -> A [64,256,13,13]
  conv3x3_k<256,256><<<64*8, 256, 0, stream>>>(B, WT5, c5b, A);
  // pool3: A -> B = feat [64,9216]
  {
    long long n = (long long)B_*256*6*6;
    maxpool_k<13,6><<<nblk(n), TPB, 0, stream>>>(A, B, (int)n);
  }
  const float* feat = B;

  gate_k<<<B_, 128, 0, stream>>>(feat, gw1, gb1, gw2, gb2, gates);

  float* part = A;
  eh1_part_k<<<dim3(8,16,2), 256, 0, stream>>>(feat, ew1, part);
  eh1_reduce_k<<<nblk(8LL*64*288), TPB, 0, stream>>>(part, eb1, h1);
  expert_h2_k<<<nblk(8LL*64*144), TPB, 0, stream>>>(h1, ew2, eb2, gates, h2);
  expert_out_k<<<nblk(64LL*1000), TPB, 0, stream>>>(h2, ew3, eb3, gates, out);
}

// Round 6
// 1881.339 us; speedup vs baseline: 8.5474x; 1.3388x over previous
//
#include <hip/hip_runtime.h>
#include <math.h>

#define TPB 256

typedef short s16x8 __attribute__((ext_vector_type(8)));
typedef float f32x4 __attribute__((ext_vector_type(4)));

// split fp32 into bf16 hi + bf16 lo (RNE both), x ~= hi + lo
__device__ inline void bsplit(float x, short& h, short& l){
  union { float f; unsigned u; } a, hf, rf;
  a.f = x;
  unsigned hu = (a.u + 0x7FFFu + ((a.u >> 16) & 1u)) >> 16;
  h = (short)hu;
  hf.u = hu << 16;
  rf.f = x - hf.f;
  l = (short)((rf.u + 0x7FFFu + ((rf.u >> 16) & 1u)) >> 16);
}

// =================== weight transpose: w[O][C9] -> wT[C9][O] (conv2) ===========
__global__ __launch_bounds__(TPB) void wtrans_k(
    const float* __restrict__ w, float* __restrict__ wT, int C9, int O)
{
  int idx = blockIdx.x*TPB + threadIdx.x;
  if (idx >= C9*O) return;
  int oc = idx % O;
  int c9 = idx / O;
  wT[idx] = w[(size_t)oc*C9 + c9];
}

// ========= weight split for MFMA convs: w[oc][c][tap] -> wh/wl[tap][oc][c] =====
__global__ __launch_bounds__(TPB) void wsplit_k(
    const float* __restrict__ w, short* __restrict__ wh, short* __restrict__ wl,
    int C, int O, int total)
{
  int idx = blockIdx.x*TPB + threadIdx.x;
  if (idx >= total) return;
  int c   = idx % C;
  int t2  = idx / C;
  int oc  = t2 % O;
  int tap = t2 / O;
  float x = w[((size_t)oc*C + c)*9 + tap];
  short h, l; bsplit(x, h, l);
  wh[idx] = h; wl[idx] = l;
}

// =================== conv1: oc-broadcast LDS scheme ===================
#define C1W 236
__global__ __launch_bounds__(256, 3) void conv1_k(
    const float* __restrict__ in, const float* __restrict__ w,
    const float* __restrict__ bias, float* __restrict__ out)
{
  __shared__ __align__(16) float s[33*C1W];
  const int oh = blockIdx.x % 55;
  const int b  = blockIdx.x / 55;
  const int oc = threadIdx.x & 63;
  const int q  = threadIdx.x >> 6;

  const int NF4 = 33*(C1W/4);
  for (int l = threadIdx.x; l < NF4; l += 256){
    int row = l / 59;
    int p4  = l % 59;
    int kh = row % 11, c = row / 11;
    int ih = oh*4 - 2 + kh;
    int iw0 = p4*4 - 4;
    float4 v = make_float4(0.f,0.f,0.f,0.f);
    if (ih >= 0 && ih < 224 && iw0 >= 0 && iw0 <= 220)
      v = *reinterpret_cast<const float4*>(in + ((size_t)(b*3 + c)*224 + ih)*224 + iw0);
    *reinterpret_cast<float4*>(&s[row*C1W + p4*4]) = v;
  }
  __syncthreads();

  float acc[14];
  float bb = bias[oc];
  #pragma unroll
  for (int j=0;j<14;++j) acc[j] = bb;
  const float* wp = w + (size_t)oc*363;
  const int base = q*56;

  #pragma unroll 1
  for (int c=0;c<3;++c){
    #pragma unroll
    for (int kh=0;kh<11;++kh){
      const float* srow = &s[(c*11+kh)*C1W + base];
      float f[68];
      #pragma unroll
      for (int v4=0; v4<17; ++v4){
        float4 t = *reinterpret_cast<const float4*>(srow + v4*4);
        f[v4*4+0]=t.x; f[v4*4+1]=t.y; f[v4*4+2]=t.z; f[v4*4+3]=t.w;
      }
      const float* wr = wp + c*121 + kh*11;
      float wv[11];
      #pragma unroll
      for (int kw=0;kw<11;++kw) wv[kw] = wr[kw];
      #pragma unroll
      for (int kw=0;kw<11;++kw)
        #pragma unroll
        for (int j=0;j<14;++j)
          acc[j] = fmaf(f[4*j + kw + 2], wv[kw], acc[j]);
    }
  }
  const int ow0 = q*14;
  const int nout = (q==3) ? 13 : 14;
  float* op = out + (((size_t)b*64 + oc)*55 + oh)*55 + ow0;
  for (int j=0;j<nout;++j) op[j] = fmaxf(acc[j], 0.f);
}

// =================== conv2 v3: 1 oc/thread + LDS weights ===================
__global__ __launch_bounds__(256, 3) void conv2_k(
    const float* __restrict__ in, const float* __restrict__ wT,
    const float* __restrict__ bias, float* __restrict__ out)
{
  const int CH = 4, ROWS = 31, STR = 36;
  __shared__ __align__(16) float si[CH*ROWS*STR];
  __shared__ __align__(16) float sw[CH*25*8];

  const int octile = blockIdx.x % 24;
  const int b      = blockIdx.x / 24;
  const int oc_l   = threadIdx.x & 7;
  const int oh     = threadIdx.x >> 3;
  const int obase  = octile*8;
  const int oc     = obase + oc_l;

  float acc[27];
  float bb = bias[oc];
  #pragma unroll
  for (int j=0;j<27;++j) acc[j] = bb;

  const float* ip = in + (size_t)b*64*27*27;

  for (int c0=0; c0<64; c0+=CH){
    __syncthreads();
    for (int l = threadIdx.x; l < CH*ROWS*STR; l += 256){
      int ch  = l / (ROWS*STR);
      int rem = l % (ROWS*STR);
      int r   = rem / STR;
      int col = rem % STR;
      int ih = r - 2, iw = col - 2;
      float v = 0.f;
      if (ih >= 0 && ih < 27 && iw >= 0 && iw < 27)
        v = ip[((size_t)(c0+ch)*27 + ih)*27 + iw];
      si[l] = v;
    }
    for (int l = threadIdx.x; l < CH*25*8; l += 256){
      int ch   = l / 200;
      int rem  = l % 200;
      int tap  = rem / 8;
      int oc_i = rem % 8;
      sw[l] = wT[((size_t)(c0+ch)*25 + tap)*192 + obase + oc_i];
    }
    __syncthreads();
    if (oh < 27){
      #pragma unroll
      for (int c=0;c<CH;++c){
        #pragma unroll
        for (int kh=0;kh<5;++kh){
          const float* row = &si[c*ROWS*STR + (oh+kh)*STR];
          float f[32];
          #pragma unroll
          for (int v=0; v<8; ++v){
            float4 qv = *reinterpret_cast<const float4*>(row + v*4);
            f[v*4+0]=qv.x; f[v*4+1]=qv.y; f[v*4+2]=qv.z; f[v*4+3]=qv.w;
          }
          float wv[5];
          #pragma unroll
          for (int kw=0;kw<5;++kw)
            wv[kw] = sw[c*200 + (kh*5+kw)*8 + oc_l];
          #pragma unroll
          for (int kw=0;kw<5;++kw)
            #pragma unroll
            for (int j=0;j<27;++j)
              acc[j] = fmaf(f[j+kw], wv[kw], acc[j]);
        }
      }
    }
  }
  if (oh < 27){
    float* op = out + (((size_t)b*192 + oc)*27 + oh)*27;
    #pragma unroll
    for (int j=0;j<27;++j)
      op[j] = fmaxf(acc[j], 0.f);
  }
}

// ============== conv3/4/5 MFMA: tap-decomposed implicit GEMM, bf16x3 ==========
// block = (oc-pass of 32, image b); 4 waves = 2 oc16 x 2 n-halves.
// LDS: zero-padded 15x20 plane, channel-minor [300 spatial][40 ch] bf16 hi/lo.
// B-frag = 1 ds_read_b128 (8 consecutive ch); A-frag = 1 global dwordx4 from
// wsplit [tap][oc][c], prefetched one tap ahead.
template<int C,int O>
__global__ __launch_bounds__(256, 2) void conv3m_k(
    const float* __restrict__ in, const short* __restrict__ whi,
    const short* __restrict__ wlo, const float* __restrict__ bias,
    float* __restrict__ out)
{
  __shared__ __align__(16) short lds[2][12000];   // [hi/lo][sp*40+ch]
  const int tid = threadIdx.x;
  const int b   = blockIdx.y;
  const int wid = tid >> 6;
  const int ln  = tid & 15;         // n-col within tile / A-row index
  const int lg  = (tid & 63) >> 4;  // lane group 0..3 (k-run / D-row group)
  const int oc0 = blockIdx.x*32 + (wid & 1)*16;
  const int ng  = wid >> 1;
  const int tbase  = ng ? 6 : 0;
  const int ntiles = ng ? 5 : 6;

  int sb[6], nn[6];
  #pragma unroll
  for (int t=0;t<6;++t){
    int n = (tbase + t)*16 + ln;
    nn[t] = n;
    int oh = n / 13, ow = n % 13;
    sb[t] = (n < 169) ? (oh*20 + ow) : 0;
  }

  f32x4 acc[6];
  const float4 bv = *reinterpret_cast<const float4*>(bias + oc0 + lg*4);
  #pragma unroll
  for (int t=0;t<6;++t) acc[t] = (f32x4){bv.x, bv.y, bv.z, bv.w};

  const float* ip = in + (size_t)b*C*169;

  #pragma unroll 1
  for (int c0=0; c0<C; c0+=32){
    __syncthreads();
    // stage 32 channels: padded plane, bf16 split, channel-minor
    for (int i = tid; i < 32*300; i += 256){
      int c   = i / 300;
      int sp  = i % 300;
      int row = sp / 20, col = sp % 20;
      float v = 0.f;
      if (row >= 1 && row <= 13 && col >= 1 && col <= 13)
        v = ip[(size_t)(c0 + c)*169 + (row-1)*13 + (col-1)];
      short h, l; bsplit(v, h, l);
      lds[0][sp*40 + c] = h;
      lds[1][sp*40 + c] = l;
    }
    __syncthreads();

    const short* wh = whi + ((size_t)oc0 + ln)*C + c0 + lg*8;
    const short* wl = wlo + ((size_t)oc0 + ln)*C + c0 + lg*8;
    s16x8 ah = *reinterpret_cast<const s16x8*>(wh);
    s16x8 al = *reinterpret_cast<const s16x8*>(wl);
    #pragma unroll 1
    for (int tap=0; tap<9; ++tap){
      s16x8 ahn = ah, aln = al;
      if (tap < 8){
        ahn = *reinterpret_cast<const s16x8*>(wh + (size_t)(tap+1)*O*C);
        aln = *reinterpret_cast<const s16x8*>(wl + (size_t)(tap+1)*O*C);
      }
      const int toff = (tap/3)*20 + (tap%3);
      #pragma unroll
      for (int t=0;t<6;++t){
        if (t < ntiles){
          int off = (sb[t] + toff)*40 + lg*8;
          s16x8 bh = *reinterpret_cast<const s16x8*>(&lds[0][off]);
          s16x8 bl = *reinterpret_cast<const s16x8*>(&lds[1][off]);
          acc[t] = __builtin_amdgcn_mfma_f32_16x16x32_bf16(al, bh, acc[t], 0,0,0);
          acc[t] = __builtin_amdgcn_mfma_f32_16x16x32_bf16(ah, bl, acc[t], 0,0,0);
          acc[t] = __builtin_amdgcn_mfma_f32_16x16x32_bf16(ah, bh, acc[t], 0,0,0);
        }
      }
      ah = ahn; al = aln;
    }
  }

  float* op = out + ((size_t)b*O + oc0)*169;
  #pragma unroll
  for (int t=0;t<6;++t){
    if (t < ntiles && nn[t] < 169){
      #pragma unroll
      for (int r=0;r<4;++r)
        op[(size_t)(lg*4 + r)*169 + nn[t]] = fmaxf(acc[t][r], 0.f);
    }
  }
}

// ---------------- 3x3 stride-2 VALID maxpool ----------------
template<int HIN,int HOUT>
__global__ __launch_bounds__(TPB) void maxpool_k(
    const float* __restrict__ in, float* __restrict__ out, int nTotal)
{
  int idx = blockIdx.x*TPB + threadIdx.x;
  if (idx >= nTotal) return;
  int ow = idx % HOUT;
  int t  = idx / HOUT;
  int oh = t % HOUT;
  int ch = t / HOUT;
  const float* p = in + ((size_t)ch*HIN + oh*2)*HIN + ow*2;
  float m = -INFINITY;
  #pragma unroll
  for (int i=0;i<3;++i)
    #pragma unroll
    for (int j=0;j<3;++j)
      m = fmaxf(m, p[i*HIN + j]);
  out[idx] = m;
}

// ---------------- gate ----------------
__global__ __launch_bounds__(128) void gate_k(
    const float* __restrict__ feat, const float* __restrict__ gw1,
    const float* __restrict__ gb1,  const float* __restrict__ gw2,
    const float* __restrict__ gb2,  float* __restrict__ gates)
{
  int b = blockIdx.x;
  int tid = threadIdx.x;
  __shared__ float g[72];
  __shared__ float logits[8];
  if (tid < 72) {
    float acc = gb1[tid];
    const float* f = feat + (size_t)b*9216;
    for (int d=0; d<9216; ++d)
      acc = fmaf(f[d], gw1[(size_t)d*72 + tid], acc);
    g[tid] = fmaxf(acc, 0.f);
  }
  __syncthreads();
  if (tid < 8) {
    float acc = gb2[tid];
    for (int j=0;j<72;++j)
      acc = fmaf(g[j], gw2[(size_t)j*8 + tid], acc);
    logits[tid] = acc;
  }
  __syncthreads();
  if (tid == 0) {
    int i1 = 0; float v1 = logits[0];
    for (int e=1;e<8;++e) if (logits[e] > v1) { v1 = logits[e]; i1 = e; }
    int i2 = -1; float v2 = -INFINITY;
    for (int e=0;e<8;++e) { if (e==i1) continue; if (logits[e] > v2) { v2 = logits[e]; i2 = e; } }
    float z  = expf(v2 - v1);
    float w1 = 1.f / (1.f + z);
    float w2 = z   / (1.f + z);
    float* gr = gates + (size_t)b*8;
    for (int e=0;e<8;++e) gr[e] = 0.f;
    gr[i1] = w1;
    gr[i2] = w2;
  }
}

// ========== expert h1 dense split-K GEMM ==========
__global__ __launch_bounds__(256, 2) void eh1_part_k(
    const float* __restrict__ feat, const float* __restrict__ ew1,
    float* __restrict__ part)
{
  const int e  = blockIdx.x;
  const int ks = blockIdx.y;
  const int nb = blockIdx.z;
  const int h0 = nb*144;
  __shared__ __align__(16) float fs[64*33];
  __shared__ __align__(16) float wsh[32*144];
  const int tid = threadIdx.x;
  const int tx = tid & 15;
  const int ty = tid >> 4;
  float acc[4][9];
  #pragma unroll
  for (int i=0;i<4;++i)
    #pragma unroll
    for (int j=0;j<9;++j) acc[i][j]=0.f;
  const float* wbase = ew1 + (size_t)e*9216*288 + h0;
  for (int d0 = ks*576; d0 < ks*576+576; d0 += 32){
    __syncthreads();
    for (int l = tid; l < 512; l += 256){
      int r = l >> 3, c = l & 7;
      float4 v = *reinterpret_cast<const float4*>(feat + (size_t)r*9216 + d0 + c*4);
      float* dst = &fs[r*33 + c*4];
      dst[0]=v.x; dst[1]=v.y; dst[2]=v.z; dst[3]=v.w;
    }
    for (int l = tid; l < 1152; l += 256){
      int r = l / 36, c = l % 36;
      *reinterpret_cast<float4*>(&wsh[r*144 + c*4]) =
        *reinterpret_cast<const float4*>(wbase + (size_t)(d0 + r)*288 + c*4);
    }
    __syncthreads();
    #pragma unroll
    for (int k=0;k<32;++k){
      float fv[4], wv[9];
      #pragma unroll
      for (int i=0;i<4;++i) fv[i] = fs[(ty*4+i)*33 + k];
      #pragma unroll
      for (int j=0;j<9;++j) wv[j] = wsh[k*144 + tx*9 + j];
      #pragma unroll
      for (int i=0;i<4;++i)
        #pragma unroll
        for (int j=0;j<9;++j)
          acc[i][j] = fmaf(fv[i], wv[j], acc[i][j]);
    }
  }
  float* pp = part + (size_t)(ks*8 + e)*64*288;
  #pragma unroll
  for (int i=0;i<4;++i)
    #pragma unroll
    for (int j=0;j<9;++j)
      pp[(ty*4+i)*288 + h0 + tx*9 + j] = acc[i][j];
}

__global__ __launch_bounds__(TPB) void eh1_reduce_k(
    const float* __restrict__ part, const float* __restrict__ eb1,
    float* __restrict__ h1)
{
  int idx = blockIdx.x*TPB + threadIdx.x;
  if (idx >= 8*64*288) return;
  int h = idx % 288;
  int e = idx / (64*288);
  float a = eb1[(size_t)e*288 + h];
  #pragma unroll
  for (int s=0;s<16;++s)
    a += part[(size_t)s*147456 + idx];
  h1[idx] = fmaxf(a, 0.f);
}

// ---------------- expert h2 / out ----------------
__global__ __launch_bounds__(TPB) void expert_h2_k(
    const float* __restrict__ h1, const float* __restrict__ ew2,
    const float* __restrict__ eb2, const float* __restrict__ gates,
    float* __restrict__ h2)
{
  int idx = blockIdx.x*TPB + threadIdx.x;
  if (idx >= 8*64*144) return;
  int k = idx % 144;
  int t = idx / 144;
  int b = t % 64;
  int e = t / 64;
  if (gates[(size_t)b*8 + e] == 0.f) return;
  float acc = eb2[(size_t)e*144 + k];
  const float* h = h1 + ((size_t)e*64 + b)*288;
  const float* w = ew2 + (size_t)e*288*144 + k;
  for (int d=0; d<288; ++d)
    acc = fmaf(h[d], w[(size_t)d*144], acc);
  h2[idx] = fmaxf(acc, 0.f);
}

__global__ __launch_bounds__(TPB) void expert_out_k(
    const float* __restrict__ h2, const float* __restrict__ ew3,
    const float* __restrict__ eb3, const float* __restrict__ gates,
    float* __restrict__ out)
{
  int idx = blockIdx.x*TPB + threadIdx.x;
  if (idx >= 64*1000) return;
  int o = idx % 1000;
  int b = idx / 1000;
  float acc = 0.f;
  const float* gr = gates + (size_t)b*8;
  for (int e=0;e<8;++e){
    float ge = gr[e];
    if (ge == 0.f) continue;
    float a = eb3[(size_t)e*1000 + o];
    const float* h = h2 + ((size_t)e*64 + b)*144;
    const float* w = ew3 + (size_t)e*144*1000 + o;
    for (int k=0;k<144;++k)
      a = fmaf(h[k], w[(size_t)k*1000], a);
    acc = fmaf(ge, a, acc);
  }
  out[idx] = acc;
}

static inline int nblk(long long n){ return (int)((n + TPB - 1) / TPB); }

extern "C" void kernel_launch(void* const* d_in, const int* in_sizes, int n_in,
                              void* d_out, int out_size, void* d_ws, size_t ws_size,
                              hipStream_t stream)
{
  const float* x   = (const float*)d_in[0];
  const float* c1w = (const float*)d_in[1];  const float* c1b = (const float*)d_in[2];
  const float* c2w = (const float*)d_in[3];  const float* c2b = (const float*)d_in[4];
  const float* c3w = (const float*)d_in[5];  const float* c3b = (const float*)d_in[6];
  const float* c4w = (const float*)d_in[7];  const float* c4b = (const float*)d_in[8];
  const float* c5w = (const float*)d_in[9];  const float* c5b = (const float*)d_in[10];
  const float* gw1 = (const float*)d_in[11]; const float* gb1 = (const float*)d_in[12];
  const float* gw2 = (const float*)d_in[13]; const float* gb2 = (const float*)d_in[14];
  const float* ew1 = (const float*)d_in[15]; const float* eb1 = (const float*)d_in[16];
  const float* ew2 = (const float*)d_in[17]; const float* eb2 = (const float*)d_in[18];
  const float* ew3 = (const float*)d_in[19]; const float* eb3 = (const float*)d_in[20];
  float* out = (float*)d_out;

  const long long A_FLOATS = 12390400LL;
  const long long B_FLOATS = 2985984LL;
  float* A = (float*)d_ws;
  float* B = A + A_FLOATS;
  float* Cg = B + B_FLOATS;
  float* gates = Cg;
  float* h1    = Cg + 512;
  float* h2    = h1 + 147456;
  // conv2 transposed weights + conv3/4/5 split weights in A tail (dead after pool1)
  float* WT2 = A +  9000000;                 // 307,200 f32
  short* WH3 = (short*)(A +  9400000);       // 663,552 sh
  short* WL3 = WH3 + 663552;                 //  (= 663,552 f32 total)
  short* WH4 = (short*)(A + 10100000);       // 884,736 sh
  short* WL4 = WH4 + 884736;
  short* WH5 = (short*)(A + 11000000);       // 589,824 sh
  short* WL5 = WH5 + 589824;
  (void)ws_size; (void)in_sizes; (void)n_in; (void)out_size;

  const int B_ = 64;

  // conv1: x -> A [64,64,55,55]
  conv1_k<<<64*55, 256, 0, stream>>>(x, c1w, c1b, A);
  // pool1: A -> B [64,64,27,27]
  {
    long long n = (long long)B_*64*27*27;
    maxpool_k<55,27><<<nblk(n), TPB, 0, stream>>>(A, B, (int)n);
  }
  // weight prep into A tail (A is dead now)
  wtrans_k<<<nblk(1600LL*192), TPB, 0, stream>>>(c2w, WT2, 1600, 192);
  wsplit_k<<<nblk(9LL*384*192), TPB, 0, stream>>>(c3w, WH3, WL3, 192, 384, 9*384*192);
  wsplit_k<<<nblk(9LL*256*384), TPB, 0, stream>>>(c4w, WH4, WL4, 384, 256, 9*256*384);
  wsplit_k<<<nblk(9LL*256*256), TPB, 0, stream>>>(c5w, WH5, WL5, 256, 256, 9*256*256);

  // conv2: B -> A [64,192,27,27]
  conv2_k<<<64*24, 256, 0, stream>>>(B, WT2, c2b, A);
  // pool2: A -> B [64,192,13,13]
  {
    long long n = (long long)B_*192*13*13;
    maxpool_k<27,13><<<nblk(n), TPB, 0, stream>>>(A, B, (int)n);
  }
  // conv3 (MFMA): B -> A [64,384,13,13]
  conv3m_k<192,384><<<dim3(12,64), 256, 0, stream>>>(B, WH3, WL3, c3b, A);
  // conv4 (MFMA): A -> B [64,256,13,13]
  conv3m_k<384,256><<<dim3(8,64), 256, 0, stream>>>(A, WH4, WL4, c4b, B);
  // conv5 (MFMA): B -> A [64,256,13,13]
  conv3m_k<256,256><<<dim3(8,64), 256, 0, stream>>>(B, WH5, WL5, c5b, A);
  // pool3: A -> B = feat [64,9216]
  {
    long long n = (long long)B_*256*6*6;
    maxpool_k<13,6><<<nblk(n), TPB, 0, stream>>>(A, B, (int)n);
  }
  const float* feat = B;

  gate_k<<<B_, 128, 0, stream>>>(feat, gw1, gb1, gw2, gb2, gates);

  float* part = A;
  eh1_part_k<<<dim3(8,16,2), 256, 0, stream>>>(feat, ew1, part);
  eh1_reduce_k<<<nblk(8LL*64*288), TPB, 0, stream>>>(part, eb1, h1);
  expert_h2_k<<<nblk(8LL*64*144), TPB, 0, stream>>>(h1, ew2, eb2, gates, h2);
  expert_out_k<<<nblk(64LL*1000), TPB, 0, stream>>>(h2, ew3, eb3, gates, out);
}

// Round 7
// 1436.858 us; speedup vs baseline: 11.1915x; 1.3093x over previous
//
#include <hip/hip_runtime.h>
#include <math.h>

#define TPB 256

typedef short s16x8 __attribute__((ext_vector_type(8)));
typedef float f32x4 __attribute__((ext_vector_type(4)));

// split fp32 into bf16 hi + bf16 lo (RNE both), x ~= hi + lo
__device__ inline void bsplit(float x, short& h, short& l){
  union { float f; unsigned u; } a, hf, rf;
  a.f = x;
  unsigned hu = (a.u + 0x7FFFu + ((a.u >> 16) & 1u)) >> 16;
  h = (short)hu;
  hf.u = hu << 16;
  rf.f = x - hf.f;
  l = (short)((rf.u + 0x7FFFu + ((rf.u >> 16) & 1u)) >> 16);
}

// ==== weight split: w[oc][c][tap] -> wh/wl[tap][oc][c] (any tap count) ====
__global__ __launch_bounds__(TPB) void wsplit_k(
    const float* __restrict__ w, short* __restrict__ wh, short* __restrict__ wl,
    int C, int O, int ntap, int total)
{
  int idx = blockIdx.x*TPB + threadIdx.x;
  if (idx >= total) return;
  int c   = idx % C;
  int t2  = idx / C;
  int oc  = t2 % O;
  int tap = t2 / O;
  float x = w[((size_t)oc*C + c)*ntap + tap];
  short h, l; bsplit(x, h, l);
  wh[idx] = h; wl[idx] = l;
}

// =================== conv1: oc-broadcast LDS scheme ===================
#define C1W 236
__global__ __launch_bounds__(256, 3) void conv1_k(
    const float* __restrict__ in, const float* __restrict__ w,
    const float* __restrict__ bias, float* __restrict__ out)
{
  __shared__ __align__(16) float s[33*C1W];
  const int oh = blockIdx.x % 55;
  const int b  = blockIdx.x / 55;
  const int oc = threadIdx.x & 63;
  const int q  = threadIdx.x >> 6;

  const int NF4 = 33*(C1W/4);
  for (int l = threadIdx.x; l < NF4; l += 256){
    int row = l / 59;
    int p4  = l % 59;
    int kh = row % 11, c = row / 11;
    int ih = oh*4 - 2 + kh;
    int iw0 = p4*4 - 4;
    float4 v = make_float4(0.f,0.f,0.f,0.f);
    if (ih >= 0 && ih < 224 && iw0 >= 0 && iw0 <= 220)
      v = *reinterpret_cast<const float4*>(in + ((size_t)(b*3 + c)*224 + ih)*224 + iw0);
    *reinterpret_cast<float4*>(&s[row*C1W + p4*4]) = v;
  }
  __syncthreads();

  float acc[14];
  float bb = bias[oc];
  #pragma unroll
  for (int j=0;j<14;++j) acc[j] = bb;
  const float* wp = w + (size_t)oc*363;
  const int base = q*56;

  #pragma unroll 1
  for (int c=0;c<3;++c){
    #pragma unroll
    for (int kh=0;kh<11;++kh){
      const float* srow = &s[(c*11+kh)*C1W + base];
      float f[68];
      #pragma unroll
      for (int v4=0; v4<17; ++v4){
        float4 t = *reinterpret_cast<const float4*>(srow + v4*4);
        f[v4*4+0]=t.x; f[v4*4+1]=t.y; f[v4*4+2]=t.z; f[v4*4+3]=t.w;
      }
      const float* wr = wp + c*121 + kh*11;
      float wv[11];
      #pragma unroll
      for (int kw=0;kw<11;++kw) wv[kw] = wr[kw];
      #pragma unroll
      for (int kw=0;kw<11;++kw)
        #pragma unroll
        for (int j=0;j<14;++j)
          acc[j] = fmaf(f[4*j + kw + 2], wv[kw], acc[j]);
    }
  }
  const int ow0 = q*14;
  const int nout = (q==3) ? 13 : 14;
  float* op = out + (((size_t)b*64 + oc)*55 + oh)*55 + ow0;
  for (int j=0;j<nout;++j) op[j] = fmaxf(acc[j], 0.f);
}

// ============== conv2 MFMA: tap-decomposed implicit GEMM, bf16x3 ==============
// block = (row-group rg of 3 output rows, image b); 4 waves, wave = 48 ocs.
// LDS: zero-padded 7x31 input tile, all 64 ch, channel-minor [217 sp][72 ch]
// (stride 72 shorts = 144B, 16B-aligned). B-frag = 1 ds_read_b128.
// A-frag = global dwordx4 from wsplit [tap][oc][c] (L2-resident, 1.2 MB).
__global__ __launch_bounds__(256, 2) void conv2m_k(
    const float* __restrict__ in, const short* __restrict__ whi,
    const short* __restrict__ wlo, const float* __restrict__ bias,
    float* __restrict__ out)
{
  __shared__ __align__(16) short lds[2][217*72];   // 62496 B
  const int tid = threadIdx.x;
  const int rg  = blockIdx.x;          // 0..8
  const int b   = blockIdx.y;
  const int wid = tid >> 6;
  const int ln  = tid & 15;
  const int lg  = (tid & 63) >> 4;
  const int oc0 = wid*48;              // wave: oc0..oc0+47 (3 M-tiles)
  const int r0  = rg*3;

  int sb[6], nn[6];
  #pragma unroll
  for (int t=0;t<6;++t){
    int n = t*16 + ln;                 // local spatial 0..95 (valid < 81)
    nn[t] = n;
    int ohl = n / 27, ow = n % 27;
    sb[t] = (n < 81) ? (ohl*31 + ow) : 0;
  }

  f32x4 acc[3][6];
  #pragma unroll
  for (int m=0;m<3;++m){
    const float4 bv = *reinterpret_cast<const float4*>(bias + oc0 + m*16 + lg*4);
    #pragma unroll
    for (int t=0;t<6;++t) acc[m][t] = (f32x4){bv.x, bv.y, bv.z, bv.w};
  }

  // ---- stage padded 7x31 tile, 64 ch, bf16 split, channel-minor ----
  const float* ip = in + (size_t)b*64*729;
  for (int i = tid; i < 217*64; i += 256){
    int c  = i / 217;
    int sp = i % 217;
    int prow = sp / 31, pcol = sp % 31;
    int ih = r0 - 2 + prow;
    int iw = pcol - 2;
    float v = 0.f;
    if (ih >= 0 && ih < 27 && iw >= 0 && iw < 27)
      v = ip[(size_t)c*729 + ih*27 + iw];
    short h, l; bsplit(v, h, l);
    lds[0][sp*72 + c] = h;
    lds[1][sp*72 + c] = l;
  }
  __syncthreads();

  #pragma unroll 1
  for (int tap=0; tap<25; ++tap){
    const int toff = (tap/5)*31 + (tap%5);
    #pragma unroll
    for (int kh2=0; kh2<64; kh2+=32){
      const size_t wo = (size_t)tap*192*64 + (size_t)kh2 + lg*8;
      s16x8 ah0 = *reinterpret_cast<const s16x8*>(whi + wo + (size_t)(oc0      + ln)*64);
      s16x8 ah1 = *reinterpret_cast<const s16x8*>(whi + wo + (size_t)(oc0 + 16 + ln)*64);
      s16x8 ah2 = *reinterpret_cast<const s16x8*>(whi + wo + (size_t)(oc0 + 32 + ln)*64);
      s16x8 al0 = *reinterpret_cast<const s16x8*>(wlo + wo + (size_t)(oc0      + ln)*64);
      s16x8 al1 = *reinterpret_cast<const s16x8*>(wlo + wo + (size_t)(oc0 + 16 + ln)*64);
      s16x8 al2 = *reinterpret_cast<const s16x8*>(wlo + wo + (size_t)(oc0 + 32 + ln)*64);
      #pragma unroll
      for (int t=0;t<6;++t){
        int off = (sb[t] + toff)*72 + kh2 + lg*8;
        s16x8 bh = *reinterpret_cast<const s16x8*>(&lds[0][off]);
        s16x8 bl = *reinterpret_cast<const s16x8*>(&lds[1][off]);
        acc[0][t] = __builtin_amdgcn_mfma_f32_16x16x32_bf16(al0, bh, acc[0][t], 0,0,0);
        acc[0][t] = __builtin_amdgcn_mfma_f32_16x16x32_bf16(ah0, bl, acc[0][t], 0,0,0);
        acc[0][t] = __builtin_amdgcn_mfma_f32_16x16x32_bf16(ah0, bh, acc[0][t], 0,0,0);
        acc[1][t] = __builtin_amdgcn_mfma_f32_16x16x32_bf16(al1, bh, acc[1][t], 0,0,0);
        acc[1][t] = __builtin_amdgcn_mfma_f32_16x16x32_bf16(ah1, bl, acc[1][t], 0,0,0);
        acc[1][t] = __builtin_amdgcn_mfma_f32_16x16x32_bf16(ah1, bh, acc[1][t], 0,0,0);
        acc[2][t] = __builtin_amdgcn_mfma_f32_16x16x32_bf16(al2, bh, acc[2][t], 0,0,0);
        acc[2][t] = __builtin_amdgcn_mfma_f32_16x16x32_bf16(ah2, bl, acc[2][t], 0,0,0);
        acc[2][t] = __builtin_amdgcn_mfma_f32_16x16x32_bf16(ah2, bh, acc[2][t], 0,0,0);
      }
    }
  }

  float* op = out + (size_t)b*192*729 + r0*27;
  #pragma unroll
  for (int m=0;m<3;++m)
    #pragma unroll
    for (int t=0;t<6;++t){
      if (nn[t] < 81){
        #pragma unroll
        for (int r=0;r<4;++r){
          int oc = oc0 + m*16 + lg*4 + r;
          op[(size_t)oc*729 + nn[t]] = fmaxf(acc[m][t][r], 0.f);
        }
      }
    }
}

// ============== conv3/4/5 MFMA: tap-decomposed implicit GEMM, bf16x3 ==========
template<int C,int O>
__global__ __launch_bounds__(256, 2) void conv3m_k(
    const float* __restrict__ in, const short* __restrict__ whi,
    const short* __restrict__ wlo, const float* __restrict__ bias,
    float* __restrict__ out)
{
  __shared__ __align__(16) short lds[2][12000];   // [hi/lo][sp*40+ch]
  const int tid = threadIdx.x;
  const int b   = blockIdx.y;
  const int wid = tid >> 6;
  const int ln  = tid & 15;
  const int lg  = (tid & 63) >> 4;
  const int oc0 = blockIdx.x*32 + (wid & 1)*16;
  const int ng  = wid >> 1;
  const int tbase  = ng ? 6 : 0;
  const int ntiles = ng ? 5 : 6;

  int sb[6], nn[6];
  #pragma unroll
  for (int t=0;t<6;++t){
    int n = (tbase + t)*16 + ln;
    nn[t] = n;
    int oh = n / 13, ow = n % 13;
    sb[t] = (n < 169) ? (oh*20 + ow) : 0;
  }

  f32x4 acc[6];
  const float4 bv = *reinterpret_cast<const float4*>(bias + oc0 + lg*4);
  #pragma unroll
  for (int t=0;t<6;++t) acc[t] = (f32x4){bv.x, bv.y, bv.z, bv.w};

  const float* ip = in + (size_t)b*C*169;

  #pragma unroll 1
  for (int c0=0; c0<C; c0+=32){
    __syncthreads();
    for (int i = tid; i < 32*300; i += 256){
      int c   = i / 300;
      int sp  = i % 300;
      int row = sp / 20, col = sp % 20;
      float v = 0.f;
      if (row >= 1 && row <= 13 && col >= 1 && col <= 13)
        v = ip[(size_t)(c0 + c)*169 + (row-1)*13 + (col-1)];
      short h, l; bsplit(v, h, l);
      lds[0][sp*40 + c] = h;
      lds[1][sp*40 + c] = l;
    }
    __syncthreads();

    const short* wh = whi + ((size_t)oc0 + ln)*C + c0 + lg*8;
    const short* wl = wlo + ((size_t)oc0 + ln)*C + c0 + lg*8;
    s16x8 ah = *reinterpret_cast<const s16x8*>(wh);
    s16x8 al = *reinterpret_cast<const s16x8*>(wl);
    #pragma unroll 1
    for (int tap=0; tap<9; ++tap){
      s16x8 ahn = ah, aln = al;
      if (tap < 8){
        ahn = *reinterpret_cast<const s16x8*>(wh + (size_t)(tap+1)*O*C);
        aln = *reinterpret_cast<const s16x8*>(wl + (size_t)(tap+1)*O*C);
      }
      const int toff = (tap/3)*20 + (tap%3);
      #pragma unroll
      for (int t=0;t<6;++t){
        if (t < ntiles){
          int off = (sb[t] + toff)*40 + lg*8;
          s16x8 bh = *reinterpret_cast<const s16x8*>(&lds[0][off]);
          s16x8 bl = *reinterpret_cast<const s16x8*>(&lds[1][off]);
          acc[t] = __builtin_amdgcn_mfma_f32_16x16x32_bf16(al, bh, acc[t], 0,0,0);
          acc[t] = __builtin_amdgcn_mfma_f32_16x16x32_bf16(ah, bl, acc[t], 0,0,0);
          acc[t] = __builtin_amdgcn_mfma_f32_16x16x32_bf16(ah, bh, acc[t], 0,0,0);
        }
      }
      ah = ahn; al = aln;
    }
  }

  float* op = out + ((size_t)b*O + oc0)*169;
  #pragma unroll
  for (int t=0;t<6;++t){
    if (t < ntiles && nn[t] < 169){
      #pragma unroll
      for (int r=0;r<4;++r)
        op[(size_t)(lg*4 + r)*169 + nn[t]] = fmaxf(acc[t][r], 0.f);
    }
  }
}

// ---------------- 3x3 stride-2 VALID maxpool ----------------
template<int HIN,int HOUT>
__global__ __launch_bounds__(TPB) void maxpool_k(
    const float* __restrict__ in, float* __restrict__ out, int nTotal)
{
  int idx = blockIdx.x*TPB + threadIdx.x;
  if (idx >= nTotal) return;
  int ow = idx % HOUT;
  int t  = idx / HOUT;
  int oh = t % HOUT;
  int ch = t / HOUT;
  const float* p = in + ((size_t)ch*HIN + oh*2)*HIN + ow*2;
  float m = -INFINITY;
  #pragma unroll
  for (int i=0;i<3;++i)
    #pragma unroll
    for (int j=0;j<3;++j)
      m = fmaxf(m, p[i*HIN + j]);
  out[idx] = m;
}

// ---------------- gate ----------------
__global__ __launch_bounds__(128) void gate_k(
    const float* __restrict__ feat, const float* __restrict__ gw1,
    const float* __restrict__ gb1,  const float* __restrict__ gw2,
    const float* __restrict__ gb2,  float* __restrict__ gates)
{
  int b = blockIdx.x;
  int tid = threadIdx.x;
  __shared__ float g[72];
  __shared__ float logits[8];
  if (tid < 72) {
    float acc = gb1[tid];
    const float* f = feat + (size_t)b*9216;
    for (int d=0; d<9216; ++d)
      acc = fmaf(f[d], gw1[(size_t)d*72 + tid], acc);
    g[tid] = fmaxf(acc, 0.f);
  }
  __syncthreads();
  if (tid < 8) {
    float acc = gb2[tid];
    for (int j=0;j<72;++j)
      acc = fmaf(g[j], gw2[(size_t)j*8 + tid], acc);
    logits[tid] = acc;
  }
  __syncthreads();
  if (tid == 0) {
    int i1 = 0; float v1 = logits[0];
    for (int e=1;e<8;++e) if (logits[e] > v1) { v1 = logits[e]; i1 = e; }
    int i2 = -1; float v2 = -INFINITY;
    for (int e=0;e<8;++e) { if (e==i1) continue; if (logits[e] > v2) { v2 = logits[e]; i2 = e; } }
    float z  = expf(v2 - v1);
    float w1 = 1.f / (1.f + z);
    float w2 = z   / (1.f + z);
    float* gr = gates + (size_t)b*8;
    for (int e=0;e<8;++e) gr[e] = 0.f;
    gr[i1] = w1;
    gr[i2] = w2;
  }
}

// ========== expert h1 dense split-K GEMM ==========
__global__ __launch_bounds__(256, 2) void eh1_part_k(
    const float* __restrict__ feat, const float* __restrict__ ew1,
    float* __restrict__ part)
{
  const int e  = blockIdx.x;
  const int ks = blockIdx.y;
  const int nb = blockIdx.z;
  const int h0 = nb*144;
  __shared__ __align__(16) float fs[64*33];
  __shared__ __align__(16) float wsh[32*144];
  const int tid = threadIdx.x;
  const int tx = tid & 15;
  const int ty = tid >> 4;
  float acc[4][9];
  #pragma unroll
  for (int i=0;i<4;++i)
    #pragma unroll
    for (int j=0;j<9;++j) acc[i][j]=0.f;
  const float* wbase = ew1 + (size_t)e*9216*288 + h0;
  for (int d0 = ks*576; d0 < ks*576+576; d0 += 32){
    __syncthreads();
    for (int l = tid; l < 512; l += 256){
      int r = l >> 3, c = l & 7;
      float4 v = *reinterpret_cast<const float4*>(feat + (size_t)r*9216 + d0 + c*4);
      float* dst = &fs[r*33 + c*4];
      dst[0]=v.x; dst[1]=v.y; dst[2]=v.z; dst[3]=v.w;
    }
    for (int l = tid; l < 1152; l += 256){
      int r = l / 36, c = l % 36;
      *reinterpret_cast<float4*>(&wsh[r*144 + c*4]) =
        *reinterpret_cast<const float4*>(wbase + (size_t)(d0 + r)*288 + c*4);
    }
    __syncthreads();
    #pragma unroll
    for (int k=0;k<32;++k){
      float fv[4], wv[9];
      #pragma unroll
      for (int i=0;i<4;++i) fv[i] = fs[(ty*4+i)*33 + k];
      #pragma unroll
      for (int j=0;j<9;++j) wv[j] = wsh[k*144 + tx*9 + j];
      #pragma unroll
      for (int i=0;i<4;++i)
        #pragma unroll
        for (int j=0;j<9;++j)
          acc[i][j] = fmaf(fv[i], wv[j], acc[i][j]);
    }
  }
  float* pp = part + (size_t)(ks*8 + e)*64*288;
  #pragma unroll
  for (int i=0;i<4;++i)
    #pragma unroll
    for (int j=0;j<9;++j)
      pp[(ty*4+i)*288 + h0 + tx*9 + j] = acc[i][j];
}

__global__ __launch_bounds__(TPB) void eh1_reduce_k(
    const float* __restrict__ part, const float* __restrict__ eb1,
    float* __restrict__ h1)
{
  int idx = blockIdx.x*TPB + threadIdx.x;
  if (idx >= 8*64*288) return;
  int h = idx % 288;
  int e = idx / (64*288);
  float a = eb1[(size_t)e*288 + h];
  #pragma unroll
  for (int s=0;s<16;++s)
    a += part[(size_t)s*147456 + idx];
  h1[idx] = fmaxf(a, 0.f);
}

// ---------------- expert h2 / out ----------------
__global__ __launch_bounds__(TPB) void expert_h2_k(
    const float* __restrict__ h1, const float* __restrict__ ew2,
    const float* __restrict__ eb2, const float* __restrict__ gates,
    float* __restrict__ h2)
{
  int idx = blockIdx.x*TPB + threadIdx.x;
  if (idx >= 8*64*144) return;
  int k = idx % 144;
  int t = idx / 144;
  int b = t % 64;
  int e = t / 64;
  if (gates[(size_t)b*8 + e] == 0.f) return;
  float acc = eb2[(size_t)e*144 + k];
  const float* h = h1 + ((size_t)e*64 + b)*288;
  const float* w = ew2 + (size_t)e*288*144 + k;
  for (int d=0; d<288; ++d)
    acc = fmaf(h[d], w[(size_t)d*144], acc);
  h2[idx] = fmaxf(acc, 0.f);
}

__global__ __launch_bounds__(TPB) void expert_out_k(
    const float* __restrict__ h2, const float* __restrict__ ew3,
    const float* __restrict__ eb3, const float* __restrict__ gates,
    float* __restrict__ out)
{
  int idx = blockIdx.x*TPB + threadIdx.x;
  if (idx >= 64*1000) return;
  int o = idx % 1000;
  int b = idx / 1000;
  float acc = 0.f;
  const float* gr = gates + (size_t)b*8;
  for (int e=0;e<8;++e){
    float ge = gr[e];
    if (ge == 0.f) continue;
    float a = eb3[(size_t)e*1000 + o];
    const float* h = h2 + ((size_t)e*64 + b)*144;
    const float* w = ew3 + (size_t)e*144*1000 + o;
    for (int k=0;k<144;++k)
      a = fmaf(h[k], w[(size_t)k*1000], a);
    acc = fmaf(ge, a, acc);
  }
  out[idx] = acc;
}

static inline int nblk(long long n){ return (int)((n + TPB - 1) / TPB); }

extern "C" void kernel_launch(void* const* d_in, const int* in_sizes, int n_in,
                              void* d_out, int out_size, void* d_ws, size_t ws_size,
                              hipStream_t stream)
{
  const float* x   = (const float*)d_in[0];
  const float* c1w = (const float*)d_in[1];  const float* c1b = (const float*)d_in[2];
  const float* c2w = (const float*)d_in[3];  const float* c2b = (const float*)d_in[4];
  const float* c3w = (const float*)d_in[5];  const float* c3b = (const float*)d_in[6];
  const float* c4w = (const float*)d_in[7];  const float* c4b = (const float*)d_in[8];
  const float* c5w = (const float*)d_in[9];  const float* c5b = (const float*)d_in[10];
  const float* gw1 = (const float*)d_in[11]; const float* gb1 = (const float*)d_in[12];
  const float* gw2 = (const float*)d_in[13]; const float* gb2 = (const float*)d_in[14];
  const float* ew1 = (const float*)d_in[15]; const float* eb1 = (const float*)d_in[16];
  const float* ew2 = (const float*)d_in[17]; const float* eb2 = (const float*)d_in[18];
  const float* ew3 = (const float*)d_in[19]; const float* eb3 = (const float*)d_in[20];
  float* out = (float*)d_out;

  const long long A_FLOATS = 12390400LL;
  const long long B_FLOATS = 2985984LL;
  float* A = (float*)d_ws;
  float* B = A + A_FLOATS;
  float* Cg = B + B_FLOATS;
  float* gates = Cg;
  float* h1    = Cg + 512;
  float* h2    = h1 + 147456;
  // split weights in A tail (written after pool1; conv outputs stay < 9M floats)
  short* WH2 = (short*)(A +  9000000);       // 307,200 sh
  short* WL2 = WH2 + 307200;                 // ends at A+9,307,200 f32
  short* WH3 = (short*)(A +  9400000);       // 663,552 sh
  short* WL3 = WH3 + 663552;
  short* WH4 = (short*)(A + 10100000);       // 884,736 sh
  short* WL4 = WH4 + 884736;
  short* WH5 = (short*)(A + 11000000);       // 589,824 sh
  short* WL5 = WH5 + 589824;
  (void)ws_size; (void)in_sizes; (void)n_in; (void)out_size;

  const int B_ = 64;

  // conv1: x -> A [64,64,55,55]
  conv1_k<<<64*55, 256, 0, stream>>>(x, c1w, c1b, A);
  // pool1: A -> B [64,64,27,27]
  {
    long long n = (long long)B_*64*27*27;
    maxpool_k<55,27><<<nblk(n), TPB, 0, stream>>>(A, B, (int)n);
  }
  // weight prep into A tail (A dead now)
  wsplit_k<<<nblk(25LL*192*64),  TPB, 0, stream>>>(c2w, WH2, WL2,  64, 192, 25, 25*192*64);
  wsplit_k<<<nblk(9LL*384*192),  TPB, 0, stream>>>(c3w, WH3, WL3, 192, 384,  9, 9*384*192);
  wsplit_k<<<nblk(9LL*256*384),  TPB, 0, stream>>>(c4w, WH4, WL4, 384, 256,  9, 9*256*384);
  wsplit_k<<<nblk(9LL*256*256),  TPB, 0, stream>>>(c5w, WH5, WL5, 256, 256,  9, 9*256*256);

  // conv2 (MFMA): B -> A [64,192,27,27]
  conv2m_k<<<dim3(9,64), 256, 0, stream>>>(B, WH2, WL2, c2b, A);
  // pool2: A -> B [64,192,13,13]
  {
    long long n = (long long)B_*192*13*13;
    maxpool_k<27,13><<<nblk(n), TPB, 0, stream>>>(A, B, (int)n);
  }
  // conv3 (MFMA): B -> A [64,384,13,13]
  conv3m_k<192,384><<<dim3(12,64), 256, 0, stream>>>(B, WH3, WL3, c3b, A);
  // conv4 (MFMA): A -> B [64,256,13,13]
  conv3m_k<384,256><<<dim3(8,64), 256, 0, stream>>>(A, WH4, WL4, c4b, B);
  // conv5 (MFMA): B -> A [64,256,13,13]
  conv3m_k<256,256><<<dim3(8,64), 256, 0, stream>>>(B, WH5, WL5, c5b, A);
  // pool3: A -> B = feat [64,9216]
  {
    long long n = (long long)B_*256*6*6;
    maxpool_k<13,6><<<nblk(n), TPB, 0, stream>>>(A, B, (int)n);
  }
  const float* feat = B;

  gate_k<<<B_, 128, 0, stream>>>(feat, gw1, gb1, gw2, gb2, gates);

  float* part = A;
  eh1_part_k<<<dim3(8,16,2), 256, 0, stream>>>(feat, ew1, part);
  eh1_reduce_k<<<nblk(8LL*64*288), TPB, 0, stream>>>(part, eb1, h1);
  expert_h2_k<<<nblk(8LL*64*144), TPB, 0, stream>>>(h1, ew2, eb2, gates, h2);
  expert_out_k<<<nblk(64LL*1000), TPB, 0, stream>>>(h2, ew3, eb3, gates, out);
}

// Round 9
// 1047.848 us; speedup vs baseline: 15.3463x; 1.3712x over previous
//
#include <hip/hip_runtime.h>
#include <math.h>

#define TPB 256

typedef short s16x8 __attribute__((ext_vector_type(8)));
typedef float f32x4 __attribute__((ext_vector_type(4)));

// split fp32 into bf16 hi + bf16 lo (RNE both), x ~= hi + lo
__device__ inline void bsplit(float x, short& h, short& l){
  union { float f; unsigned u; } a, hf, rf;
  a.f = x;
  unsigned hu = (a.u + 0x7FFFu + ((a.u >> 16) & 1u)) >> 16;
  h = (short)hu;
  hf.u = hu << 16;
  rf.f = x - hf.f;
  l = (short)((rf.u + 0x7FFFu + ((rf.u >> 16) & 1u)) >> 16);
}

// ==== weight split: w[oc][c][tap] -> wh/wl[tap][oc][c] (any tap count) ====
__global__ __launch_bounds__(TPB) void wsplit_k(
    const float* __restrict__ w, short* __restrict__ wh, short* __restrict__ wl,
    int C, int O, int ntap, int total)
{
  int idx = blockIdx.x*TPB + threadIdx.x;
  if (idx >= total) return;
  int c   = idx % C;
  int t2  = idx / C;
  int oc  = t2 % O;
  int tap = t2 / O;
  float x = w[((size_t)oc*C + c)*ntap + tap];
  short h, l; bsplit(x, h, l);
  wh[idx] = h; wl[idx] = l;
}

// ==== transpose w[O][K] -> wT[K][O] (for gw1: gw1[9216][72] -> GT1[72][9216]) ====
__global__ __launch_bounds__(TPB) void wtrans_k(
    const float* __restrict__ w, float* __restrict__ wT, int K, int O)
{
  int idx = blockIdx.x*TPB + threadIdx.x;
  if (idx >= K*O) return;
  int oc = idx % O;
  int k  = idx / O;
  wT[idx] = w[(size_t)oc*K + k];
}

// =================== conv1: oc-broadcast LDS scheme ===================
#define C1W 236
__global__ __launch_bounds__(256, 3) void conv1_k(
    const float* __restrict__ in, const float* __restrict__ w,
    const float* __restrict__ bias, float* __restrict__ out)
{
  __shared__ __align__(16) float s[33*C1W];
  const int oh = blockIdx.x % 55;
  const int b  = blockIdx.x / 55;
  const int oc = threadIdx.x & 63;
  const int q  = threadIdx.x >> 6;

  const int NF4 = 33*(C1W/4);
  for (int l = threadIdx.x; l < NF4; l += 256){
    int row = l / 59;
    int p4  = l % 59;
    int kh = row % 11, c = row / 11;
    int ih = oh*4 - 2 + kh;
    int iw0 = p4*4 - 4;
    float4 v = make_float4(0.f,0.f,0.f,0.f);
    if (ih >= 0 && ih < 224 && iw0 >= 0 && iw0 <= 220)
      v = *reinterpret_cast<const float4*>(in + ((size_t)(b*3 + c)*224 + ih)*224 + iw0);
    *reinterpret_cast<float4*>(&s[row*C1W + p4*4]) = v;
  }
  __syncthreads();

  float acc[14];
  float bb = bias[oc];
  #pragma unroll
  for (int j=0;j<14;++j) acc[j] = bb;
  const float* wp = w + (size_t)oc*363;
  const int base = q*56;

  #pragma unroll 1
  for (int c=0;c<3;++c){
    #pragma unroll
    for (int kh=0;kh<11;++kh){
      const float* srow = &s[(c*11+kh)*C1W + base];
      float f[68];
      #pragma unroll
      for (int v4=0; v4<17; ++v4){
        float4 t = *reinterpret_cast<const float4*>(srow + v4*4);
        f[v4*4+0]=t.x; f[v4*4+1]=t.y; f[v4*4+2]=t.z; f[v4*4+3]=t.w;
      }
      const float* wr = wp + c*121 + kh*11;
      float wv[11];
      #pragma unroll
      for (int kw=0;kw<11;++kw) wv[kw] = wr[kw];
      #pragma unroll
      for (int kw=0;kw<11;++kw)
        #pragma unroll
        for (int j=0;j<14;++j)
          acc[j] = fmaf(f[4*j + kw + 2], wv[kw], acc[j]);
    }
  }
  const int ow0 = q*14;
  const int nout = (q==3) ? 13 : 14;
  float* op = out + (((size_t)b*64 + oc)*55 + oh)*55 + ow0;
  for (int j=0;j<nout;++j) op[j] = fmaxf(acc[j], 0.f);
}

// ============== conv2 MFMA: tap-decomposed implicit GEMM, bf16x3 ==============
__global__ __launch_bounds__(256, 2) void conv2m_k(
    const float* __restrict__ in, const short* __restrict__ whi,
    const short* __restrict__ wlo, const float* __restrict__ bias,
    float* __restrict__ out)
{
  __shared__ __align__(16) short lds[2][217*72];   // 62496 B
  const int tid = threadIdx.x;
  const int rg  = blockIdx.x;          // 0..8
  const int b   = blockIdx.y;
  const int wid = tid >> 6;
  const int ln  = tid & 15;
  const int lg  = (tid & 63) >> 4;
  const int oc0 = wid*48;
  const int r0  = rg*3;

  int sb[6], nn[6];
  #pragma unroll
  for (int t=0;t<6;++t){
    int n = t*16 + ln;
    nn[t] = n;
    int ohl = n / 27, ow = n % 27;
    sb[t] = (n < 81) ? (ohl*31 + ow) : 0;
  }

  f32x4 acc[3][6];
  #pragma unroll
  for (int m=0;m<3;++m){
    const float4 bv = *reinterpret_cast<const float4*>(bias + oc0 + m*16 + lg*4);
    #pragma unroll
    for (int t=0;t<6;++t) acc[m][t] = (f32x4){bv.x, bv.y, bv.z, bv.w};
  }

  const float* ip = in + (size_t)b*64*729;
  for (int i = tid; i < 217*64; i += 256){
    int c  = i / 217;
    int sp = i % 217;
    int prow = sp / 31, pcol = sp % 31;
    int ih = r0 - 2 + prow;
    int iw = pcol - 2;
    float v = 0.f;
    if (ih >= 0 && ih < 27 && iw >= 0 && iw < 27)
      v = ip[(size_t)c*729 + ih*27 + iw];
    short h, l; bsplit(v, h, l);
    lds[0][sp*72 + c] = h;
    lds[1][sp*72 + c] = l;
  }
  __syncthreads();

  #pragma unroll 1
  for (int tap=0; tap<25; ++tap){
    const int toff = (tap/5)*31 + (tap%5);
    #pragma unroll
    for (int kh2=0; kh2<64; kh2+=32){
      const size_t wo = (size_t)tap*192*64 + (size_t)kh2 + lg*8;
      s16x8 ah0 = *reinterpret_cast<const s16x8*>(whi + wo + (size_t)(oc0      + ln)*64);
      s16x8 ah1 = *reinterpret_cast<const s16x8*>(whi + wo + (size_t)(oc0 + 16 + ln)*64);
      s16x8 ah2 = *reinterpret_cast<const s16x8*>(whi + wo + (size_t)(oc0 + 32 + ln)*64);
      s16x8 al0 = *reinterpret_cast<const s16x8*>(wlo + wo + (size_t)(oc0      + ln)*64);
      s16x8 al1 = *reinterpret_cast<const s16x8*>(wlo + wo + (size_t)(oc0 + 16 + ln)*64);
      s16x8 al2 = *reinterpret_cast<const s16x8*>(wlo + wo + (size_t)(oc0 + 32 + ln)*64);
      #pragma unroll
      for (int t=0;t<6;++t){
        int off = (sb[t] + toff)*72 + kh2 + lg*8;
        s16x8 bh = *reinterpret_cast<const s16x8*>(&lds[0][off]);
        s16x8 bl = *reinterpret_cast<const s16x8*>(&lds[1][off]);
        acc[0][t] = __builtin_amdgcn_mfma_f32_16x16x32_bf16(al0, bh, acc[0][t], 0,0,0);
        acc[0][t] = __builtin_amdgcn_mfma_f32_16x16x32_bf16(ah0, bl, acc[0][t], 0,0,0);
        acc[0][t] = __builtin_amdgcn_mfma_f32_16x16x32_bf16(ah0, bh, acc[0][t], 0,0,0);
        acc[1][t] = __builtin_amdgcn_mfma_f32_16x16x32_bf16(al1, bh, acc[1][t], 0,0,0);
        acc[1][t] = __builtin_amdgcn_mfma_f32_16x16x32_bf16(ah1, bl, acc[1][t], 0,0,0);
        acc[1][t] = __builtin_amdgcn_mfma_f32_16x16x32_bf16(ah1, bh, acc[1][t], 0,0,0);
        acc[2][t] = __builtin_amdgcn_mfma_f32_16x16x32_bf16(al2, bh, acc[2][t], 0,0,0);
        acc[2][t] = __builtin_amdgcn_mfma_f32_16x16x32_bf16(ah2, bl, acc[2][t], 0,0,0);
        acc[2][t] = __builtin_amdgcn_mfma_f32_16x16x32_bf16(ah2, bh, acc[2][t], 0,0,0);
      }
    }
  }

  float* op = out + (size_t)b*192*729 + r0*27;
  #pragma unroll
  for (int m=0;m<3;++m)
    #pragma unroll
    for (int t=0;t<6;++t){
      if (nn[t] < 81){
        #pragma unroll
        for (int r=0;r<4;++r){
          int oc = oc0 + m*16 + lg*4 + r;
          op[(size_t)oc*729 + nn[t]] = fmaxf(acc[m][t][r], 0.f);
        }
      }
    }
}

// ============== conv3/4/5 MFMA: tap-decomposed implicit GEMM, bf16x3 ==========
template<int C,int O>
__global__ __launch_bounds__(256, 2) void conv3m_k(
    const float* __restrict__ in, const short* __restrict__ whi,
    const short* __restrict__ wlo, const float* __restrict__ bias,
    float* __restrict__ out)
{
  __shared__ __align__(16) short lds[2][12000];
  const int tid = threadIdx.x;
  const int b   = blockIdx.y;
  const int wid = tid >> 6;
  const int ln  = tid & 15;
  const int lg  = (tid & 63) >> 4;
  const int oc0 = blockIdx.x*32 + (wid & 1)*16;
  const int ng  = wid >> 1;
  const int tbase  = ng ? 6 : 0;
  const int ntiles = ng ? 5 : 6;

  int sb[6], nn[6];
  #pragma unroll
  for (int t=0;t<6;++t){
    int n = (tbase + t)*16 + ln;
    nn[t] = n;
    int oh = n / 13, ow = n % 13;
    sb[t] = (n < 169) ? (oh*20 + ow) : 0;
  }

  f32x4 acc[6];
  const float4 bv = *reinterpret_cast<const float4*>(bias + oc0 + lg*4);
  #pragma unroll
  for (int t=0;t<6;++t) acc[t] = (f32x4){bv.x, bv.y, bv.z, bv.w};

  const float* ip = in + (size_t)b*C*169;

  #pragma unroll 1
  for (int c0=0; c0<C; c0+=32){
    __syncthreads();
    for (int i = tid; i < 32*300; i += 256){
      int c   = i / 300;
      int sp  = i % 300;
      int row = sp / 20, col = sp % 20;
      float v = 0.f;
      if (row >= 1 && row <= 13 && col >= 1 && col <= 13)
        v = ip[(size_t)(c0 + c)*169 + (row-1)*13 + (col-1)];
      short h, l; bsplit(v, h, l);
      lds[0][sp*40 + c] = h;
      lds[1][sp*40 + c] = l;
    }
    __syncthreads();

    const short* wh = whi + ((size_t)oc0 + ln)*C + c0 + lg*8;
    const short* wl = wlo + ((size_t)oc0 + ln)*C + c0 + lg*8;
    s16x8 ah = *reinterpret_cast<const s16x8*>(wh);
    s16x8 al = *reinterpret_cast<const s16x8*>(wl);
    #pragma unroll 1
    for (int tap=0; tap<9; ++tap){
      s16x8 ahn = ah, aln = al;
      if (tap < 8){
        ahn = *reinterpret_cast<const s16x8*>(wh + (size_t)(tap+1)*O*C);
        aln = *reinterpret_cast<const s16x8*>(wl + (size_t)(tap+1)*O*C);
      }
      const int toff = (tap/3)*20 + (tap%3);
      #pragma unroll
      for (int t=0;t<6;++t){
        if (t < ntiles){
          int off = (sb[t] + toff)*40 + lg*8;
          s16x8 bh = *reinterpret_cast<const s16x8*>(&lds[0][off]);
          s16x8 bl = *reinterpret_cast<const s16x8*>(&lds[1][off]);
          acc[t] = __builtin_amdgcn_mfma_f32_16x16x32_bf16(al, bh, acc[t], 0,0,0);
          acc[t] = __builtin_amdgcn_mfma_f32_16x16x32_bf16(ah, bl, acc[t], 0,0,0);
          acc[t] = __builtin_amdgcn_mfma_f32_16x16x32_bf16(ah, bh, acc[t], 0,0,0);
        }
      }
      ah = ahn; al = aln;
    }
  }

  float* op = out + ((size_t)b*O + oc0)*169;
  #pragma unroll
  for (int t=0;t<6;++t){
    if (t < ntiles && nn[t] < 169){
      #pragma unroll
      for (int r=0;r<4;++r)
        op[(size_t)(lg*4 + r)*169 + nn[t]] = fmaxf(acc[t][r], 0.f);
    }
  }
}

// ---------------- 3x3 stride-2 VALID maxpool ----------------
template<int HIN,int HOUT>
__global__ __launch_bounds__(TPB) void maxpool_k(
    const float* __restrict__ in, float* __restrict__ out, int nTotal)
{
  int idx = blockIdx.x*TPB + threadIdx.x;
  if (idx >= nTotal) return;
  int ow = idx % HOUT;
  int t  = idx / HOUT;
  int oh = t % HOUT;
  int ch = t / HOUT;
  const float* p = in + ((size_t)ch*HIN + oh*2)*HIN + ow*2;
  float m = -INFINITY;
  #pragma unroll
  for (int i=0;i<3;++i)
    #pragma unroll
    for (int j=0;j<3;++j)
      m = fmaxf(m, p[i*HIN + j]);
  out[idx] = m;
}

// ---------------- gate layer 1: one wave per (b,h), shuffle reduce ----------------
__global__ __launch_bounds__(256) void gate1_k(
    const float* __restrict__ feat, const float* __restrict__ gw1T,
    const float* __restrict__ gb1, float* __restrict__ g)
{
  const int b    = blockIdx.x;
  const int h    = blockIdx.y*4 + (threadIdx.x >> 6);
  const int lane = threadIdx.x & 63;
  const float* f = feat + (size_t)b*9216;
  const float* w = gw1T + (size_t)h*9216;
  float s = 0.f;
  #pragma unroll
  for (int it=0; it<36; ++it){
    int d = it*256 + lane*4;
    float4 fv = *reinterpret_cast<const float4*>(f + d);
    float4 wv = *reinterpret_cast<const float4*>(w + d);
    s = fmaf(fv.x, wv.x, s);
    s = fmaf(fv.y, wv.y, s);
    s = fmaf(fv.z, wv.z, s);
    s = fmaf(fv.w, wv.w, s);
  }
  #pragma unroll
  for (int off=32; off; off>>=1) s += __shfl_down(s, off, 64);
  if (lane == 0) g[(size_t)b*72 + h] = fmaxf(s + gb1[h], 0.f);
}

// ---------------- gate layer 2 + top-2 softmax (128 thr: 72-load needs >64!) ----
__global__ __launch_bounds__(128) void gate2_k(
    const float* __restrict__ g, const float* __restrict__ gw2,
    const float* __restrict__ gb2, float* __restrict__ gates)
{
  const int b = blockIdx.x;
  const int tid = threadIdx.x;
  __shared__ float gs[72];
  __shared__ float logits[8];
  if (tid < 72) gs[tid] = g[(size_t)b*72 + tid];
  __syncthreads();
  if (tid < 8) {
    float acc = gb2[tid];
    for (int j=0;j<72;++j)
      acc = fmaf(gs[j], gw2[(size_t)j*8 + tid], acc);
    logits[tid] = acc;
  }
  __syncthreads();
  if (tid == 0) {
    int i1 = 0; float v1 = logits[0];
    for (int e=1;e<8;++e) if (logits[e] > v1) { v1 = logits[e]; i1 = e; }
    int i2 = -1; float v2 = -INFINITY;
    for (int e=0;e<8;++e) { if (e==i1) continue; if (logits[e] > v2) { v2 = logits[e]; i2 = e; } }
    float z  = expf(v2 - v1);
    float w1 = 1.f / (1.f + z);
    float w2 = z   / (1.f + z);
    float* gr = gates + (size_t)b*8;
    for (int e=0;e<8;++e) gr[e] = 0.f;
    gr[i1] = w1;
    gr[i2] = w2;
  }
}

// ========== expert h1 dense split-K GEMM ==========
__global__ __launch_bounds__(256, 2) void eh1_part_k(
    const float* __restrict__ feat, const float* __restrict__ ew1,
    float* __restrict__ part)
{
  const int e  = blockIdx.x;
  const int ks = blockIdx.y;
  const int nb = blockIdx.z;
  const int h0 = nb*144;
  __shared__ __align__(16) float fs[64*33];
  __shared__ __align__(16) float wsh[32*144];
  const int tid = threadIdx.x;
  const int tx = tid & 15;
  const int ty = tid >> 4;
  float acc[4][9];
  #pragma unroll
  for (int i=0;i<4;++i)
    #pragma unroll
    for (int j=0;j<9;++j) acc[i][j]=0.f;
  const float* wbase = ew1 + (size_t)e*9216*288 + h0;
  for (int d0 = ks*576; d0 < ks*576+576; d0 += 32){
    __syncthreads();
    for (int l = tid; l < 512; l += 256){
      int r = l >> 3, c = l & 7;
      float4 v = *reinterpret_cast<const float4*>(feat + (size_t)r*9216 + d0 + c*4);
      float* dst = &fs[r*33 + c*4];
      dst[0]=v.x; dst[1]=v.y; dst[2]=v.z; dst[3]=v.w;
    }
    for (int l = tid; l < 1152; l += 256){
      int r = l / 36, c = l % 36;
      *reinterpret_cast<float4*>(&wsh[r*144 + c*4]) =
        *reinterpret_cast<const float4*>(wbase + (size_t)(d0 + r)*288 + c*4);
    }
    __syncthreads();
    #pragma unroll
    for (int k=0;k<32;++k){
      float fv[4], wv[9];
      #pragma unroll
      for (int i=0;i<4;++i) fv[i] = fs[(ty*4+i)*33 + k];
      #pragma unroll
      for (int j=0;j<9;++j) wv[j] = wsh[k*144 + tx*9 + j];
      #pragma unroll
      for (int i=0;i<4;++i)
        #pragma unroll
        for (int j=0;j<9;++j)
          acc[i][j] = fmaf(fv[i], wv[j], acc[i][j]);
    }
  }
  float* pp = part + (size_t)(ks*8 + e)*64*288;
  #pragma unroll
  for (int i=0;i<4;++i)
    #pragma unroll
    for (int j=0;j<9;++j)
      pp[(ty*4+i)*288 + h0 + tx*9 + j] = acc[i][j];
}

__global__ __launch_bounds__(TPB) void eh1_reduce_k(
    const float* __restrict__ part, const float* __restrict__ eb1,
    float* __restrict__ h1)
{
  int idx = blockIdx.x*TPB + threadIdx.x;
  if (idx >= 8*64*288) return;
  int h = idx % 288;
  int e = idx / (64*288);
  float a = eb1[(size_t)e*288 + h];
  #pragma unroll
  for (int s=0;s<16;++s)
    a += part[(size_t)s*147456 + idx];
  h1[idx] = fmaxf(a, 0.f);
}

// ---------------- expert h2 / out ----------------
__global__ __launch_bounds__(TPB) void expert_h2_k(
    const float* __restrict__ h1, const float* __restrict__ ew2,
    const float* __restrict__ eb2, const float* __restrict__ gates,
    float* __restrict__ h2)
{
  int idx = blockIdx.x*TPB + threadIdx.x;
  if (idx >= 8*64*144) return;
  int k = idx % 144;
  int t = idx / 144;
  int b = t % 64;
  int e = t / 64;
  if (gates[(size_t)b*8 + e] == 0.f) return;
  float acc = eb2[(size_t)e*144 + k];
  const float* h = h1 + ((size_t)e*64 + b)*288;
  const float* w = ew2 + (size_t)e*288*144 + k;
  for (int d=0; d<288; ++d)
    acc = fmaf(h[d], w[(size_t)d*144], acc);
  h2[idx] = fmaxf(acc, 0.f);
}

__global__ __launch_bounds__(TPB) void expert_out_k(
    const float* __restrict__ h2, const float* __restrict__ ew3,
    const float* __restrict__ eb3, const float* __restrict__ gates,
    float* __restrict__ out)
{
  int idx = blockIdx.x*TPB + threadIdx.x;
  if (idx >= 64*1000) return;
  int o = idx % 1000;
  int b = idx / 1000;
  float acc = 0.f;
  const float* gr = gates + (size_t)b*8;
  for (int e=0;e<8;++e){
    float ge = gr[e];
    if (ge == 0.f) continue;
    float a = eb3[(size_t)e*1000 + o];
    const float* h = h2 + ((size_t)e*64 + b)*144;
    const float* w = ew3 + (size_t)e*144*1000 + o;
    for (int k=0;k<144;++k)
      a = fmaf(h[k], w[(size_t)k*1000], a);
    acc = fmaf(ge, a, acc);
  }
  out[idx] = acc;
}

static inline int nblk(long long n){ return (int)((n + TPB - 1) / TPB); }

extern "C" void kernel_launch(void* const* d_in, const int* in_sizes, int n_in,
                              void* d_out, int out_size, void* d_ws, size_t ws_size,
                              hipStream_t stream)
{
  const float* x   = (const float*)d_in[0];
  const float* c1w = (const float*)d_in[1];  const float* c1b = (const float*)d_in[2];
  const float* c2w = (const float*)d_in[3];  const float* c2b = (const float*)d_in[4];
  const float* c3w = (const float*)d_in[5];  const float* c3b = (const float*)d_in[6];
  const float* c4w = (const float*)d_in[7];  const float* c4b = (const float*)d_in[8];
  const float* c5w = (const float*)d_in[9];  const float* c5b = (const float*)d_in[10];
  const float* gw1 = (const float*)d_in[11]; const float* gb1 = (const float*)d_in[12];
  const float* gw2 = (const float*)d_in[13]; const float* gb2 = (const float*)d_in[14];
  const float* ew1 = (const float*)d_in[15]; const float* eb1 = (const float*)d_in[16];
  const float* ew2 = (const float*)d_in[17]; const float* eb2 = (const float*)d_in[18];
  const float* ew3 = (const float*)d_in[19]; const float* eb3 = (const float*)d_in[20];
  float* out = (float*)d_out;

  const long long A_FLOATS = 12390400LL;
  const long long B_FLOATS = 2985984LL;
  float* A = (float*)d_ws;
  float* B = A + A_FLOATS;
  float* Cg = B + B_FLOATS;
  float* gates = Cg;                         // 512
  float* h1    = Cg + 512;                   // 147456
  float* h2    = h1 + 147456;                // 73728
  float* gbuf  = h2 + 73728;                 // 4608 (g[64][72])
  // split weights + gw1 transpose in A tail (written after pool1; conv
  // outputs & eh1 partials stay < 9M floats)
  short* WH2 = (short*)(A +  9000000);       // 307,200 sh
  short* WL2 = WH2 + 307200;
  short* WH3 = (short*)(A +  9400000);       // 663,552 sh
  short* WL3 = WH3 + 663552;
  short* WH4 = (short*)(A + 10100000);       // 884,736 sh
  short* WL4 = WH4 + 884736;
  short* WH5 = (short*)(A + 11000000);       // 589,824 sh
  short* WL5 = WH5 + 589824;
  float* GT1 = A + 11600000;                 // 663,552 f32, ends 12,263,552
  (void)ws_size; (void)in_sizes; (void)n_in; (void)out_size;

  const int B_ = 64;

  // conv1: x -> A [64,64,55,55]
  conv1_k<<<64*55, 256, 0, stream>>>(x, c1w, c1b, A);
  // pool1: A -> B [64,64,27,27]
  {
    long long n = (long long)B_*64*27*27;
    maxpool_k<55,27><<<nblk(n), TPB, 0, stream>>>(A, B, (int)n);
  }
  // weight prep into A tail (A dead now)
  wsplit_k<<<nblk(25LL*192*64),  TPB, 0, stream>>>(c2w, WH2, WL2,  64, 192, 25, 25*192*64);
  wsplit_k<<<nblk(9LL*384*192),  TPB, 0, stream>>>(c3w, WH3, WL3, 192, 384,  9, 9*384*192);
  wsplit_k<<<nblk(9LL*256*384),  TPB, 0, stream>>>(c4w, WH4, WL4, 384, 256,  9, 9*256*384);
  wsplit_k<<<nblk(9LL*256*256),  TPB, 0, stream>>>(c5w, WH5, WL5, 256, 256,  9, 9*256*256);
  wtrans_k<<<nblk(72LL*9216),    TPB, 0, stream>>>(gw1, GT1, 72, 9216);

  // conv2 (MFMA): B -> A [64,192,27,27]
  conv2m_k<<<dim3(9,64), 256, 0, stream>>>(B, WH2, WL2, c2b, A);
  // pool2: A -> B [64,192,13,13]
  {
    long long n = (long long)B_*192*13*13;
    maxpool_k<27,13><<<nblk(n), TPB, 0, stream>>>(A, B, (int)n);
  }
  // conv3 (MFMA): B -> A [64,384,13,13]
  conv3m_k<192,384><<<dim3(12,64), 256, 0, stream>>>(B, WH3, WL3, c3b, A);
  // conv4 (MFMA): A -> B [64,256,13,13]
  conv3m_k<384,256><<<dim3(8,64), 256, 0, stream>>>(A, WH4, WL4, c4b, B);
  // conv5 (MFMA): B -> A [64,256,13,13]
  conv3m_k<256,256><<<dim3(8,64), 256, 0, stream>>>(B, WH5, WL5, c5b, A);
  // pool3: A -> B = feat [64,9216]
  {
    long long n = (long long)B_*256*6*6;
    maxpool_k<13,6><<<nblk(n), TPB, 0, stream>>>(A, B, (int)n);
  }
  const float* feat = B;

  // gate: wave-per-(b,h) GEMV + tiny top-2 kernel
  gate1_k<<<dim3(64,18), 256, 0, stream>>>(feat, GT1, gb1, gbuf);
  gate2_k<<<64, 128, 0, stream>>>(gbuf, gw2, gb2, gates);

  float* part = A;
  eh1_part_k<<<dim3(8,16,2), 256, 0, stream>>>(feat, ew1, part);
  eh1_reduce_k<<<nblk(8LL*64*288), TPB, 0, stream>>>(part, eb1, h1);
  expert_h2_k<<<nblk(8LL*64*144), TPB, 0, stream>>>(h1, ew2, eb2, gates, h2);
  expert_out_k<<<nblk(64LL*1000), TPB, 0, stream>>>(h2, ew3, eb3, gates, out);
}